// Round 13
// baseline (330.031 us; speedup 1.0000x reference)
//
#include <hip/hip_runtime.h>

typedef unsigned short u16;
typedef __attribute__((ext_vector_type(2))) float f32x2;
typedef __attribute__((ext_vector_type(4))) float f32x4;
typedef __attribute__((ext_vector_type(8))) short s16x8;
typedef __attribute__((ext_vector_type(8))) u16 u16x8;
typedef __attribute__((ext_vector_type(4))) u16 u16x4;

#define NB 16
#define CD 512
#define NS 4096
#define NHD 8

#define SBAR  __builtin_amdgcn_s_barrier()
#define SCHED __builtin_amdgcn_sched_barrier(0)
#define LGKM0 asm volatile("s_waitcnt lgkmcnt(0)" ::: "memory")
#define PRIO1 __builtin_amdgcn_s_setprio(1)
#define PRIO0 __builtin_amdgcn_s_setprio(0)

__device__ __forceinline__ float bf2f(u16 u){
  union { unsigned int i; float f; } z; z.i = ((unsigned int)u) << 16; return z.f;
}
__device__ __forceinline__ u16 f2bf(float f){
  union { float f; unsigned int i; } z; z.f = f;
  unsigned int i = z.i;
  return (u16)((i + 0x7fffu + ((i >> 16) & 1u)) >> 16);
}
__device__ __forceinline__ float gelu_f(float x){
  return 0.5f * x * (1.0f + erff(x * 0.70710678118654752440f));
}
__device__ __forceinline__ void gl_lds16(const u16* g, u16* l){
  __builtin_amdgcn_global_load_lds((const __attribute__((address_space(1))) void*)(g),
                                   (__attribute__((address_space(3))) void*)(l), 16, 0, 0);
}

// ---------------- K0: weights -> bf16 (g1 folded into w_qkv) ----------------
__global__ void prep_w_k(const float* __restrict__ wqkv, const float* __restrict__ g1,
                         const float* __restrict__ wout, u16* __restrict__ w1b,
                         u16* __restrict__ w2b){
  int i = blockIdx.x * 256 + threadIdx.x;
  if (i < 1536*512) {
    w1b[i] = f2bf(wqkv[i] * g1[i & 511]);
  } else {
    int j = i - 1536*512;
    w2b[j] = f2bf(wout[j]);
  }
}

// ------- K1: ChanLN over c, single global read via big-LDS staging ---------
__global__ __launch_bounds__(512) void ln1t_k(const float* __restrict__ fmap,
                                              u16* __restrict__ xlnT){
  int b = blockIdx.y, n0 = blockIdx.x * 32;
  int t = threadIdx.x;
  int lane = t & 63, wv = t >> 6;
  __shared__ float Lb[512][36];
  __shared__ u16 Tt[64][36];
  __shared__ float red1[8][8][4], red2[8][8][4];
  __shared__ float mean_s[32], rstd_s[32];

  int ng = t & 7;
  float s1[4] = {0,0,0,0}, s2[4] = {0,0,0,0};
  const float* fb = fmap + ((size_t)b*CD)*NS + n0 + ng*4;
  #pragma unroll
  for (int it = 0; it < 8; ++it){
    int q = it*512 + t;
    int c = q >> 3;
    f32x4 v = *(const f32x4*)&fb[(size_t)c*NS];
    *(f32x4*)&Lb[c][ng*4] = v;
    #pragma unroll
    for (int j = 0; j < 4; ++j){ s1[j] += v[j]; s2[j] += v[j]*v[j]; }
  }
  #pragma unroll
  for (int off = 8; off < 64; off <<= 1)
    #pragma unroll
    for (int j = 0; j < 4; ++j){
      s1[j] += __shfl_xor(s1[j], off, 64);
      s2[j] += __shfl_xor(s2[j], off, 64);
    }
  if (lane < 8){
    #pragma unroll
    for (int j = 0; j < 4; ++j){ red1[wv][lane][j] = s1[j]; red2[wv][lane][j] = s2[j]; }
  }
  __syncthreads();
  if (t < 32){
    int g = t >> 2, j = t & 3;
    float a = 0.f, bq = 0.f;
    #pragma unroll
    for (int w = 0; w < 8; ++w){ a += red1[w][g][j]; bq += red2[w][g][j]; }
    float mn = a * (1.f/512.f);
    float var = bq * (1.f/512.f) - mn*mn;
    mean_s[t] = mn; rstd_s[t] = rsqrtf(var + 1e-5f);
  }
  __syncthreads();

  for (int ct = 0; ct < 8; ++ct){
    {
      int cl = t >> 3, n4 = (t & 7) * 4;
      f32x4 v = *(const f32x4*)&Lb[ct*64 + cl][n4];
      u16x4 pk;
      #pragma unroll
      for (int j = 0; j < 4; ++j)
        pk[j] = f2bf((v[j] - mean_s[n4+j]) * rstd_s[n4+j]);
      *(u16x4*)&Tt[cl][n4] = pk;
    }
    __syncthreads();
    {
      int nr = t >> 4, c4 = t & 15;
      u16x4 w;
      #pragma unroll
      for (int j = 0; j < 4; ++j) w[j] = Tt[c4*4 + j][nr];
      *(u16x4*)&xlnT[((size_t)b*NS + n0 + nr)*CD + ct*64 + c4*4] = w;
    }
    __syncthreads();
  }
}

// ---------- K2: 256x256 GEMM, BK=64, lean 2-phase counted-vmcnt ------------
// Same loop as r12 (115us, 0 conflicts). NEW: C-epilogue staged through LDS
// (rows padded to 260 u16 -> 0-conflict writes) + coalesced u16x8 stores
// (was 64 scalar 2B stores/thread).
__global__ __launch_bounds__(512) void gemm1_k(const u16* __restrict__ A,
                                               const u16* __restrict__ Bm,
                                               u16* __restrict__ Cm){
  __shared__ u16 lds[66560];   // loop: [2 slot][4 half][8192]; epilogue: 256x260
  auto L = [&](int slot, int half) -> u16* { return lds + ((slot<<2)+half)*8192; };
  int bi = blockIdx.x;
  int xcd = bi & 7, r2 = bi >> 3;
  int gi = r2 / 6, yy = r2 - gi*6;
  int g  = gi*8 + xcd;
  int x  = g & 15, z = g >> 4;
  int o0 = yy*256, bn0 = x*256;
  int t = threadIdx.x;
  int lane = t & 63, wv = t >> 6;
  int wm = wv >> 2, wn = wv & 3;
  int fr = lane & 15, fg = lane >> 4;
  const u16* Ab = A + (size_t)o0*512;
  const u16* Bb = Bm + ((size_t)z*NS + bn0)*512;
  int li8 = lane >> 3, scn = lane & 7;

  f32x4 acc[8][4];
  #pragma unroll
  for (int i=0;i<8;++i)
    #pragma unroll
    for (int j=0;j<4;++j) acc[i][j] = (f32x4){0.f,0.f,0.f,0.f};
  s16x8 afr[4][2];
  s16x8 bfr[2][2][2];

  auto stH = [&](int slot, int half, int kt){
    #pragma unroll
    for (int it=0; it<2; ++it){
      int li = it*64 + wv*8 + li8;
      int q  = scn ^ (li & 7);
      int row;
      if (half < 2) row = ((li>>6)<<7) + half*64 + (li & 63);       // A
      else          row = ((li>>5)<<6) + (half-2)*32 + (li & 31);   // B
      const u16* G = (half < 2) ? Ab : Bb;
      gl_lds16(G + (size_t)row*512 + kt + q*8, L(slot,half) + it*4096 + wv*512);
    }
  };
  auto ldA = [&](int slot, int mq){
    #pragma unroll
    for (int mr=0;mr<4;++mr)
      #pragma unroll
      for (int ks=0;ks<2;++ks){
        int li = wm*64 + mr*16 + fr;
        int c8 = (ks*4+fg) ^ (li & 7);
        afr[mr][ks] = *(const s16x8*)(L(slot,mq) + li*64 + c8*8);
      }
  };
  auto ldB = [&](int slot, int nq){
    #pragma unroll
    for (int nr=0;nr<2;++nr)
      #pragma unroll
      for (int ks=0;ks<2;++ks){
        int li = wn*32 + nr*16 + fr;
        int c8 = (ks*4+fg) ^ (li & 7);
        bfr[nq][nr][ks] = *(const s16x8*)(L(slot,2+nq) + li*64 + c8*8);
      }
  };
  auto mm = [&](int mq, int nq){
    #pragma unroll
    for (int mr=0;mr<4;++mr)
      #pragma unroll
      for (int nr=0;nr<2;++nr)
        #pragma unroll
        for (int ks=0;ks<2;++ks)
          acc[mq*4+mr][nq*2+nr] = __builtin_amdgcn_mfma_f32_16x16x32_bf16(
              afr[mr][ks], bfr[nq][nr][ks], acc[mq*4+mr][nq*2+nr], 0,0,0);
  };

  // prologue: tile 0, halves in consumption order Ah0,Bh0,Bh1,Ah1
  stH(0,0,0); stH(0,2,0); stH(0,3,0); stH(0,1,0);
  asm volatile("s_waitcnt vmcnt(2)" ::: "memory");
  SBAR; SCHED;

  #pragma unroll
  for (int kt=0; kt<8; ++kt){
    int slot = kt & 1, ns = slot ^ 1, kn = (kt+1)*64;
    bool F = kt < 7;
    // P1: quads (m0,n0) + (m0,n1)
    ldA(slot,0); ldB(slot,0); ldB(slot,1);
    if (F){ stH(ns,0,kn); stH(ns,2,kn); stH(ns,3,kn); }
    PRIO1; mm(0,0); mm(0,1); PRIO0;
    if (F) asm volatile("s_waitcnt vmcnt(6)" ::: "memory");
    else   asm volatile("s_waitcnt vmcnt(0)" ::: "memory");
    SBAR; SCHED;
    // P2: quads (m1,n1) + (m1,n0)
    ldA(slot,1);
    if (F) stH(ns,1,kn);
    PRIO1; mm(1,1); mm(1,0); PRIO0;
    if (F) asm volatile("s_waitcnt vmcnt(2)" ::: "memory");
    SBAR; SCHED;
  }

  // ---- epilogue: stage 256x256 bf16 tile in LDS (pad 260), coalesced out --
  // loop's final SBAR passed; all gl_lds drained by kt=7's vmcnt(0); all
  // ds_reads consumed by MFMAs before each wave's last barrier -> LDS free.
  #pragma unroll
  for (int mq=0;mq<2;++mq)
    #pragma unroll
    for (int mr=0;mr<4;++mr)
      #pragma unroll
      for (int nq=0;nq<2;++nq)
        #pragma unroll
        for (int nr=0;nr<2;++nr){
          int row = wm*128 + mq*64 + mr*16 + fg*4;
          int col = wn*64 + nq*32 + nr*16 + fr;
          #pragma unroll
          for (int r=0;r<4;++r)
            lds[(row+r)*260 + col] = f2bf(acc[mq*4+mr][nq*2+nr][r]);
        }
  SBAR;
  size_t cb = (size_t)z * 1536 * NS;
  #pragma unroll
  for (int p=0;p<16;++p){
    int idx = p*512 + t;
    int row = idx >> 5, colv = (idx & 31)*8;
    u16x8 v = *(const u16x8*)&lds[row*260 + colv];
    *(u16x8*)&Cm[cb + (size_t)(o0+row)*NS + bn0 + colv] = v;
  }
}

// ------ K6: full-column GEMM (512x128) + fused final ChanLN -> d_out -------
// NEW: fp32 out-epilogue staged through LDS in 8 chunks of [64][130] f32
// (pad 130 -> conflict-light), coalesced f32x4 stores.
__global__ __launch_bounds__(512, 2) void gemm2ln_k(const u16* __restrict__ A,
                                                    const u16* __restrict__ Bm,
                                                    const float* __restrict__ g2,
                                                    float* __restrict__ out){
  __shared__ u16 lds[3][20480];   // slot: A 256 lines (32KB), B 64 lines (8KB)
  int x = blockIdx.x, z = blockIdx.y;
  int n0 = x*128;
  int t = threadIdx.x;
  int lane = t & 63, wv = t >> 6;
  int wm = wv >> 1, wn = wv & 1;
  int fr = lane & 15, fg = lane >> 4;
  const u16* Ab = A;
  const u16* Bb = Bm + ((size_t)z*NS + n0)*512;

  int l8  = lane >> 3;
  int c8d = lane & 7;

  f32x4 acc[8][4];
  #pragma unroll
  for (int i=0;i<8;++i)
    #pragma unroll
    for (int j=0;j<4;++j) acc[i][j] = (f32x4){0.f,0.f,0.f,0.f};
  s16x8 afr[4], bfr[4];

  auto stA = [&](int slot, int kt, int bt){
    int L  = bt*64 + wv*8 + l8;
    int q  = c8d ^ (l8 & 7);
    int r  = (q >> 2)*256 + L;
    int col = kt + (q & 3)*8;
    gl_lds16(Ab + (size_t)r*512 + col, &lds[slot][(bt*64 + wv*8)*64]);
  };
  auto stB = [&](int slot, int kt){
    int L  = wv*8 + l8;
    int q  = c8d ^ (l8 & 7);
    int r  = (q >> 2)*64 + L;
    int col = kt + (q & 3)*8;
    gl_lds16(Bb + (size_t)r*512 + col, &lds[slot][16384 + (wv*8)*64]);
  };
  auto ldA = [&](int slot, int h){
    #pragma unroll
    for (int mi=0;mi<4;++mi){
      int R = wm*128 + (h*4+mi)*16 + fr;
      int L = R & 255, half = R >> 8;
      int c8 = (half*4 + fg) ^ (L & 7);
      afr[mi] = *(const s16x8*)&lds[slot][L*64 + c8*8];
    }
  };
  auto ldB = [&](int slot){
    #pragma unroll
    for (int nj=0;nj<4;++nj){
      int R = wn*64 + nj*16 + fr;
      int L = R & 63, half = R >> 6;
      int c8 = (half*4 + fg) ^ (L & 7);
      bfr[nj] = *(const s16x8*)&lds[slot][16384 + L*64 + c8*8];
    }
  };
  auto mm16 = [&](int h){
    #pragma unroll
    for (int mi=0;mi<4;++mi)
      #pragma unroll
      for (int nj=0;nj<4;++nj)
        acc[h*4+mi][nj] = __builtin_amdgcn_mfma_f32_16x16x32_bf16(
            afr[mi], bfr[nj], acc[h*4+mi][nj], 0,0,0);
  };

  #pragma unroll
  for (int p=0;p<2;++p){ stA(p,p*32,0); stA(p,p*32,1); stB(p,p*32); stA(p,p*32,2); stA(p,p*32,3); }
  asm volatile("s_waitcnt vmcnt(5)" ::: "memory");
  SBAR; SCHED;

  #pragma unroll
  for (int kt=0; kt<16; ++kt){
    int slot = kt%3;
    ldA(slot,0); ldB(slot);
    if (kt<14){
      int ns = (kt+2)%3, kn = (kt+2)*32;
      stA(ns,kn,0); stA(ns,kn,1); stB(ns,kn); stA(ns,kn,2); stA(ns,kn,3);
    }
    PRIO1; mm16(0); PRIO0;
    ldA(slot,1);
    PRIO1; mm16(1); PRIO0;
    if (kt<14)       asm volatile("s_waitcnt vmcnt(5)" ::: "memory");
    else if (kt==14) asm volatile("s_waitcnt vmcnt(0)" ::: "memory");
    SBAR; SCHED;
  }

  // ---- fused LN2: stats over all 512 rows per n-col ----
  __syncthreads();
  float* red1 = (float*)&lds[0][0];
  float* red2 = red1 + 512;
  float* ms   = red2 + 512;
  float* rs   = ms + 128;
  float s1[4], s2[4];
  #pragma unroll
  for (int nj=0;nj<4;++nj){
    float a = 0.f, b2 = 0.f;
    #pragma unroll
    for (int mi=0;mi<8;++mi)
      #pragma unroll
      for (int r=0;r<4;++r){ float v = acc[mi][nj][r]; a += v; b2 += v*v; }
    s1[nj] = a; s2[nj] = b2;
  }
  #pragma unroll
  for (int off=16; off<64; off<<=1)
    #pragma unroll
    for (int nj=0;nj<4;++nj){
      s1[nj] += __shfl_xor(s1[nj], off, 64);
      s2[nj] += __shfl_xor(s2[nj], off, 64);
    }
  if (fg == 0){
    #pragma unroll
    for (int nj=0;nj<4;++nj){
      int c = wn*64 + nj*16 + fr;
      red1[wm*128 + c] = s1[nj];
      red2[wm*128 + c] = s2[nj];
    }
  }
  __syncthreads();
  if (t < 128){
    float a  = red1[t] + red1[128+t] + red1[256+t] + red1[384+t];
    float b2 = red2[t] + red2[128+t] + red2[256+t] + red2[384+t];
    float mn = a * (1.f/512.f);
    float var = b2 * (1.f/512.f) - mn*mn;
    ms[t] = mn; rs[t] = rsqrtf(var + 1e-5f);
  }
  __syncthreads();
  float mc[4], rc[4];
  #pragma unroll
  for (int nj=0;nj<4;++nj){
    int c = wn*64 + nj*16 + fr;
    mc[nj] = ms[c]; rc[nj] = rs[c];
  }
  __syncthreads();   // stats consumed; LDS free for staging

  // ---- staged epilogue: 8 chunks of [64 rows][130 f32] ----
  float* sm = (float*)&lds[0][0];
  float* obase = out + (size_t)z*CD*NS + n0;
  #pragma unroll
  for (int ch=0; ch<8; ++ch){
    if (wm == (ch>>1)){
      int mlo = (ch&1)*4;
      #pragma unroll
      for (int mi2=0;mi2<4;++mi2)
        #pragma unroll
        for (int r=0;r<4;++r){
          int rl = mi2*16 + fg*4 + r;
          int row = wm*128 + (mlo+mi2)*16 + fg*4 + r;
          float gg = g2[row];
          #pragma unroll
          for (int nj=0;nj<4;++nj)
            sm[rl*130 + wn*64 + nj*16 + fr] = (acc[mlo+mi2][nj][r] - mc[nj])*rc[nj]*gg;
        }
    }
    __syncthreads();
    #pragma unroll
    for (int p=0;p<4;++p){
      int idx = p*512 + t;
      int rl = idx >> 5, cl = (idx & 31)*4;
      f32x4 v = *(const f32x4*)&sm[rl*130 + cl];
      *(f32x4*)&obase[(size_t)(ch*64 + rl)*NS + cl] = v;
    }
    __syncthreads();
  }
}

// ------- K4: context partials (no-max k-softmax: |k| <= ~3, exp safe) ------
__global__ __launch_bounds__(256) void ctxpart_k(const u16* __restrict__ qkv,
                                                 float* __restrict__ part,
                                                 float* __restrict__ mS){
  int chunk = blockIdx.x, bh = blockIdx.y;
  int b = bh >> 3, h = bh & 7;
  int t = threadIdx.x;
  int lane = t & 63, wv = t >> 6;
  int fr = lane & 15, fg = lane >> 4;
  __shared__ u16 KT[64*128];
  __shared__ u16 VT[64*128];
  __shared__ float invn_s[128];
  const u16* kb = qkv + ((size_t)(b*1536 + 512  + h*64))*NS;
  const u16* vb = qkv + ((size_t)(b*1536 + 1024 + h*64))*NS;
  int d = t >> 2, q = t & 3;

  float sloc = 0.f;

  f32x4 acc[4][4];
  #pragma unroll
  for (int i=0;i<4;++i)
    #pragma unroll
    for (int j=0;j<4;++j) acc[i][j] = (f32x4){0.f,0.f,0.f,0.f};

  for (int nt = 0; nt < 4; ++nt){
    int n0 = chunk*512 + nt*128;
    if (nt) __syncthreads();
    u16x8 kreg[4];
    #pragma unroll
    for (int s = 0; s < 4; ++s){
      int c0 = q*32 + s*8;
      u16x8 vv = *(const u16x8*)&vb[(size_t)d*NS + n0 + c0];
      *(u16x8*)&VT[d*128 + (c0 ^ ((d&7)<<3))] = vv;
      kreg[s] = *(const u16x8*)&kb[(size_t)d*NS + n0 + c0];
    }
    __syncthreads();
    {
      int col = t >> 1, half = t & 1;
      float ss = 0.f;
      #pragma unroll
      for (int e2 = 0; e2 < 32; ++e2){
        int e = half*32 + e2;
        float xv = bf2f(VT[e*128 + (col ^ ((e&7)<<3))]);
        ss += xv*xv;
      }
      ss += __shfl_xor(ss, 1, 64);
      if (half == 0) invn_s[col] = rsqrtf(ss);
    }
    __syncthreads();
    #pragma unroll
    for (int s = 0; s < 4; ++s){
      int c0 = q*32 + s*8;
      u16x8 kk = kreg[s];
      u16x8 ek;
      #pragma unroll
      for (int j = 0; j < 8; ++j){
        float e = __expf(bf2f(kk[j]));
        sloc += e;
        ek[j] = f2bf(e * invn_s[c0 + j]);
      }
      *(u16x8*)&KT[d*128 + (c0 ^ ((d&7)<<3))] = ek;
    }
    __syncthreads();
    int kc = wv*32 + fg*8;
    s16x8 af[4], bfr[4];
    #pragma unroll
    for (int i=0;i<4;++i){
      int ra = i*16 + fr;
      af[i]  = *(const s16x8*)&KT[ra*128 + (kc ^ ((ra&7)<<3))];
      bfr[i] = *(const s16x8*)&VT[ra*128 + (kc ^ ((ra&7)<<3))];
    }
    #pragma unroll
    for (int i=0;i<4;++i)
      #pragma unroll
      for (int j=0;j<4;++j)
        acc[i][j] = __builtin_amdgcn_mfma_f32_16x16x32_bf16(af[i], bfr[j], acc[i][j], 0,0,0);
  }

  sloc += __shfl_xor(sloc, 1, 64);
  sloc += __shfl_xor(sloc, 2, 64);
  if (q == 0){
    size_t mb = ((size_t)bh*8 + chunk)*128;
    mS[mb + d]      = 0.0f;
    mS[mb + 64 + d] = sloc;
  }

  float* buf0 = (float*)KT;
  float* buf1 = (float*)VT;
  auto dump = [&](float* bf){
    #pragma unroll
    for (int i=0;i<4;++i)
      #pragma unroll
      for (int j=0;j<4;++j)
        #pragma unroll
        for (int r=0;r<4;++r) bf[((i*4+j)*4+r)*64 + lane] = acc[i][j][r];
  };
  auto addin = [&](float* bf){
    #pragma unroll
    for (int i=0;i<4;++i)
      #pragma unroll
      for (int j=0;j<4;++j)
        #pragma unroll
        for (int r=0;r<4;++r) acc[i][j][r] += bf[((i*4+j)*4+r)*64 + lane];
  };
  __syncthreads();
  if (wv==1) dump(buf0);
  if (wv==3) dump(buf1);
  __syncthreads();
  if (wv==0) addin(buf0);
  if (wv==2) addin(buf1);
  __syncthreads();
  if (wv==2) dump(buf0);
  __syncthreads();
  if (wv==0){
    addin(buf0);
    float* pp = part + ((size_t)bh*8 + chunk)*4096;
    #pragma unroll
    for (int i=0;i<4;++i)
      #pragma unroll
      for (int j=0;j<4;++j)
        #pragma unroll
        for (int r=0;r<4;++r)
          pp[(i*16+fg*4+r)*64 + j*16+fr] = acc[i][j][r];
  }
}

// ---- K4b: merge 8 chunk partials with online-softmax scales -> ctx --------
__global__ void ctxred_k(const float* __restrict__ part, const float* __restrict__ mS,
                         float* __restrict__ ctx){
  int bh = blockIdx.x, t = threadIdx.x;
  __shared__ float fs[8][64];
  if (t < 64){
    int d = t;
    float mc[8];
    float mx = -3.0e38f;
    #pragma unroll
    for (int c=0;c<8;++c){ mc[c] = mS[((size_t)bh*8 + c)*128 + d]; mx = fmaxf(mx, mc[c]); }
    float es[8]; float denom = 0.f;
    #pragma unroll
    for (int c=0;c<8;++c){
      es[c] = __expf(mc[c] - mx);
      denom += es[c] * mS[((size_t)bh*8 + c)*128 + 64 + d];
    }
    float inv = 1.0f / (denom * 4096.0f);
    #pragma unroll
    for (int c=0;c<8;++c) fs[c][d] = es[c] * inv;
  }
  __syncthreads();
  #pragma unroll
  for (int i=0;i<16;++i){
    int idx = t + i*256;
    int d = idx >> 6;
    float s = 0.f;
    #pragma unroll
    for (int ch=0; ch<8; ++ch) s += fs[ch][d] * part[((size_t)bh*8 + ch)*4096 + idx];
    ctx[(size_t)bh*4096 + idx] = s;
  }
}

// ------- K5: out = softmax_feat(q)*scale @ ctx  via MFMA, GELU, gT[b][n][c] -
__global__ __launch_bounds__(256) void attnout_k(const u16* __restrict__ qkv,
                                                 const float* __restrict__ ctx,
                                                 u16* __restrict__ gT){
  int bh = blockIdx.y;
  int b = bh >> 3, h = bh & 7;
  int n0 = blockIdx.x * 256;
  int t = threadIdx.x;
  int lane = t & 63, wv = t >> 6;
  int fr = lane & 15, fg = lane >> 4;
  __shared__ u16 P[256][72];
  __shared__ u16 cT[64][72];

  const float* cs = ctx + (size_t)bh*4096;
  #pragma unroll
  for (int i=0;i<16;++i){
    int idx = i*256 + t;
    int d = idx >> 6, e = idx & 63;
    cT[e][d] = f2bf(cs[idx]);
  }

  const u16* qb = qkv + ((size_t)(b*1536 + h*64))*NS + n0 + t;
  float p[64];
  #pragma unroll
  for (int d=0; d<64; ++d) p[d] = bf2f(qb[(size_t)d*NS]);
  float m = p[0];
  #pragma unroll
  for (int d=1; d<64; ++d) m = fmaxf(m, p[d]);
  float s = 0.f;
  #pragma unroll
  for (int d=0; d<64; ++d){ p[d] = __expf(p[d]-m); s += p[d]; }
  float inv = 0.125f / s;
  #pragma unroll
  for (int d0=0; d0<8; ++d0){
    u16x8 pk;
    #pragma unroll
    for (int j=0;j<8;++j) pk[j] = f2bf(p[d0*8+j] * inv);
    *(u16x8*)&P[t][d0*8] = pk;
  }
  __syncthreads();

  f32x4 acc[4][4];
  #pragma unroll
  for (int i=0;i<4;++i)
    #pragma unroll
    for (int j=0;j<4;++j) acc[i][j] = (f32x4){0.f,0.f,0.f,0.f};
  #pragma unroll
  for (int k=0; k<2; ++k){
    s16x8 af[4], bfr[4];
    #pragma unroll
    for (int i=0;i<4;++i){
      af[i]  = *(const s16x8*)&P[wv*64 + i*16 + fr][k*32 + fg*8];
      bfr[i] = *(const s16x8*)&cT[i*16 + fr][k*32 + fg*8];
    }
    #pragma unroll
    for (int i=0;i<4;++i)
      #pragma unroll
      for (int j=0;j<4;++j)
        acc[i][j] = __builtin_amdgcn_mfma_f32_16x16x32_bf16(af[i], bfr[j], acc[i][j], 0,0,0);
  }

  #pragma unroll
  for (int i=0;i<4;++i)
    #pragma unroll
    for (int j=0;j<4;++j)
      #pragma unroll
      for (int r=0;r<4;++r)
        P[wv*64 + i*16 + fg*4 + r][j*16 + fr] = f2bf(gelu_f(acc[i][j][r]));

  int sub = lane >> 4, e4 = (lane & 15) * 4;
  #pragma unroll
  for (int it=0; it<16; ++it){
    int row = wv*64 + it*4 + sub;
    *(u16x4*)&gT[((size_t)b*NS + n0 + row)*CD + h*64 + e4] = *(u16x4*)&P[row][e4];
  }
}

extern "C" void kernel_launch(void* const* d_in, const int* in_sizes, int n_in,
                              void* d_out, int out_size, void* d_ws, size_t ws_size,
                              hipStream_t stream) {
  const float* fmap = (const float*)d_in[0];
  const float* g1   = (const float*)d_in[1];
  const float* wqkv = (const float*)d_in[2];
  const float* wout = (const float*)d_in[3];
  const float* g2   = (const float*)d_in[4];
  float* out = (float*)d_out;

  char* ws = (char*)d_ws;
  size_t off = 0;
  auto alloc = [&](size_t bytes) -> void* {
    void* p = ws + off;
    off += (bytes + 255) & ~(size_t)255;
    return p;
  };
  u16*   qkv  = (u16*)alloc((size_t)16*1536*4096*2);
  u16*   xlnT = (u16*)alloc((size_t)16*4096*512*2);    // reused as gT
  u16*   gT   = xlnT;
  float* part = (float*)alloc((size_t)128*8*4096*4);
  float* mS   = (float*)alloc((size_t)128*8*128*4);
  float* ctx  = (float*)alloc((size_t)128*4096*4);
  u16*   w1b  = (u16*)alloc((size_t)1536*512*2);
  u16*   w2b  = (u16*)alloc((size_t)512*512*2);
  if (off > ws_size) return;

  prep_w_k<<<4096, 256, 0, stream>>>(wqkv, g1, wout, w1b, w2b);
  ln1t_k<<<dim3(128,16), 512, 0, stream>>>(fmap, xlnT);
  gemm1_k<<<1536, 512, 0, stream>>>(w1b, xlnT, qkv);
  ctxpart_k<<<dim3(8,128), 256, 0, stream>>>(qkv, part, mS);
  ctxred_k<<<128, 256, 0, stream>>>(part, mS, ctx);
  attnout_k<<<dim3(16,128), 256, 0, stream>>>(qkv, ctx, gT);
  gemm2ln_k<<<dim3(32,16), 512, 0, stream>>>(w2b, gT, g2, out);
}

// Round 14
// 328.272 us; speedup vs baseline: 1.0054x; 1.0054x over previous
//
#include <hip/hip_runtime.h>

typedef unsigned short u16;
typedef __attribute__((ext_vector_type(2))) float f32x2;
typedef __attribute__((ext_vector_type(4))) float f32x4;
typedef __attribute__((ext_vector_type(8))) short s16x8;
typedef __attribute__((ext_vector_type(8))) u16 u16x8;
typedef __attribute__((ext_vector_type(4))) u16 u16x4;

#define NB 16
#define CD 512
#define NS 4096
#define NHD 8

#define SBAR  __builtin_amdgcn_s_barrier()
#define SCHED __builtin_amdgcn_sched_barrier(0)
#define LGKM0 asm volatile("s_waitcnt lgkmcnt(0)" ::: "memory")
#define PRIO1 __builtin_amdgcn_s_setprio(1)
#define PRIO0 __builtin_amdgcn_s_setprio(0)

__device__ __forceinline__ float bf2f(u16 u){
  union { unsigned int i; float f; } z; z.i = ((unsigned int)u) << 16; return z.f;
}
__device__ __forceinline__ u16 f2bf(float f){
  union { float f; unsigned int i; } z; z.f = f;
  unsigned int i = z.i;
  return (u16)((i + 0x7fffu + ((i >> 16) & 1u)) >> 16);
}
__device__ __forceinline__ float gelu_f(float x){
  return 0.5f * x * (1.0f + erff(x * 0.70710678118654752440f));
}
__device__ __forceinline__ void gl_lds16(const u16* g, u16* l){
  __builtin_amdgcn_global_load_lds((const __attribute__((address_space(1))) void*)(g),
                                   (__attribute__((address_space(3))) void*)(l), 16, 0, 0);
}

// ---------------- K0: weights -> bf16 (g1 folded into w_qkv) ----------------
__global__ void prep_w_k(const float* __restrict__ wqkv, const float* __restrict__ g1,
                         const float* __restrict__ wout, u16* __restrict__ w1b,
                         u16* __restrict__ w2b){
  int i = blockIdx.x * 256 + threadIdx.x;
  if (i < 1536*512) {
    w1b[i] = f2bf(wqkv[i] * g1[i & 511]);
  } else {
    int j = i - 1536*512;
    w2b[j] = f2bf(wout[j]);
  }
}

// ------- K1: ChanLN over c, single global read via big-LDS staging ---------
__global__ __launch_bounds__(512) void ln1t_k(const float* __restrict__ fmap,
                                              u16* __restrict__ xlnT){
  int b = blockIdx.y, n0 = blockIdx.x * 32;
  int t = threadIdx.x;
  int lane = t & 63, wv = t >> 6;
  __shared__ float Lb[512][36];
  __shared__ u16 Tt[64][36];
  __shared__ float red1[8][8][4], red2[8][8][4];
  __shared__ float mean_s[32], rstd_s[32];

  int ng = t & 7;
  float s1[4] = {0,0,0,0}, s2[4] = {0,0,0,0};
  const float* fb = fmap + ((size_t)b*CD)*NS + n0 + ng*4;
  #pragma unroll
  for (int it = 0; it < 8; ++it){
    int q = it*512 + t;
    int c = q >> 3;
    f32x4 v = *(const f32x4*)&fb[(size_t)c*NS];
    *(f32x4*)&Lb[c][ng*4] = v;
    #pragma unroll
    for (int j = 0; j < 4; ++j){ s1[j] += v[j]; s2[j] += v[j]*v[j]; }
  }
  #pragma unroll
  for (int off = 8; off < 64; off <<= 1)
    #pragma unroll
    for (int j = 0; j < 4; ++j){
      s1[j] += __shfl_xor(s1[j], off, 64);
      s2[j] += __shfl_xor(s2[j], off, 64);
    }
  if (lane < 8){
    #pragma unroll
    for (int j = 0; j < 4; ++j){ red1[wv][lane][j] = s1[j]; red2[wv][lane][j] = s2[j]; }
  }
  __syncthreads();
  if (t < 32){
    int g = t >> 2, j = t & 3;
    float a = 0.f, bq = 0.f;
    #pragma unroll
    for (int w = 0; w < 8; ++w){ a += red1[w][g][j]; bq += red2[w][g][j]; }
    float mn = a * (1.f/512.f);
    float var = bq * (1.f/512.f) - mn*mn;
    mean_s[t] = mn; rstd_s[t] = rsqrtf(var + 1e-5f);
  }
  __syncthreads();

  for (int ct = 0; ct < 8; ++ct){
    {
      int cl = t >> 3, n4 = (t & 7) * 4;
      f32x4 v = *(const f32x4*)&Lb[ct*64 + cl][n4];
      u16x4 pk;
      #pragma unroll
      for (int j = 0; j < 4; ++j)
        pk[j] = f2bf((v[j] - mean_s[n4+j]) * rstd_s[n4+j]);
      *(u16x4*)&Tt[cl][n4] = pk;
    }
    __syncthreads();
    {
      int nr = t >> 4, c4 = t & 15;
      u16x4 w;
      #pragma unroll
      for (int j = 0; j < 4; ++j) w[j] = Tt[c4*4 + j][nr];
      *(u16x4*)&xlnT[((size_t)b*NS + n0 + nr)*CD + ct*64 + c4*4] = w;
    }
    __syncthreads();
  }
}

// ---------- K2: 256x128 GEMM, BK=32, 3-slot ring, 2 blocks/CU --------------
// 256 thr / 4 waves (2M x 2N), per-wave 128x64 (42.7 FLOP/LDS-byte). LDS
// 72KB -> 2 blocks/CU: cross-block wave overlap absorbs gate/barrier stalls
// (m114). r8-family 128B-line layout (measured 0-conflict): A 256x32 as
// lines[128][64u16], slot s=((r>>7)*4+kc)^(L&7); B 128x32 as lines[64][64].
// Source pre-swizzled (rule #21), dest linear. Counted vmcnt(6): stage 2
// tiles ahead, never drain mid-loop.
__global__ __launch_bounds__(256, 2) void gemm1_k(const u16* __restrict__ A,
                                                  const u16* __restrict__ Bm,
                                                  u16* __restrict__ Cm){
  __shared__ u16 lds[3][12288];   // slot: A[0..8192) 128 lines, B[8192..12288) 64 lines
  int bi = blockIdx.x;
  int xcd = bi & 7, r2 = bi >> 3;          // 384 per XCD
  int oo  = r2 % 6;                        // o fastest: B panel L2-reuse x6
  int x   = (r2 / 6) & 31;
  int zl  = r2 / 192;                      // 0..1
  int z   = xcd*2 + zl;
  int o0 = oo*256, bn0 = x*128;
  int t = threadIdx.x;
  int lane = t & 63, wv = t >> 6;
  int wm = wv >> 1, wn = wv & 1;
  int fr = lane & 15, fg = lane >> 4;
  const u16* Ab = A + (size_t)o0*512;
  const u16* Bb = Bm + ((size_t)z*NS + bn0)*512;
  int sl = t & 7;                          // dest 16B-slot within line

  f32x4 acc[8][4];
  #pragma unroll
  for (int i=0;i<8;++i)
    #pragma unroll
    for (int j=0;j<4;++j) acc[i][j] = (f32x4){0.f,0.f,0.f,0.f};
  s16x8 afr[8], bfr[4];

  auto stA = [&](int slot, int kt){        // 16KB: 4 issues x 256 thr x 16B
    #pragma unroll
    for (int it=0; it<4; ++it){
      int gsl = it*256 + t;                // 0..1023
      int L   = gsl >> 3;                  // line 0..127
      int q   = sl ^ (L & 7);
      int r   = (q >> 2)*128 + L;
      int kc  = q & 3;
      gl_lds16(Ab + (size_t)r*512 + kt + kc*8, &lds[slot][(it*256 + (t & ~63))*8 ]);
    }
  };
  auto stB = [&](int slot, int kt){        // 8KB: 2 issues
    #pragma unroll
    for (int it=0; it<2; ++it){
      int gsl = it*256 + t;                // 0..511
      int L   = gsl >> 3;                  // line 0..63
      int q   = sl ^ (L & 7);
      int n   = (q >> 2)*64 + L;
      int kc  = q & 3;
      gl_lds16(Bb + (size_t)n*512 + kt + kc*8, &lds[slot][8192 + (it*256 + (t & ~63))*8 ]);
    }
  };
  auto ldA = [&](int slot){
    #pragma unroll
    for (int mr=0;mr<8;++mr){
      int L = mr*16 + fr;                  // R = wm*128 + L, hi = wm
      int s = (wm*4 + fg) ^ (L & 7);
      afr[mr] = *(const s16x8*)&lds[slot][L*64 + s*8];
    }
  };
  auto ldB = [&](int slot){
    #pragma unroll
    for (int nj=0;nj<4;++nj){
      int L = nj*16 + fr;                  // n = wn*64 + L, hi = wn
      int s = (wn*4 + fg) ^ (L & 7);
      bfr[nj] = *(const s16x8*)&lds[slot][8192 + L*64 + s*8];
    }
  };

  // prologue: tiles 0,1 (6 loads each); wait tile 0 (6 outstanding)
  stA(0,0);  stB(0,0);
  stA(1,32); stB(1,32);
  asm volatile("s_waitcnt vmcnt(6)" ::: "memory");
  SBAR; SCHED;

  #pragma unroll
  for (int kt=0; kt<16; ++kt){
    int slot = kt % 3;
    ldA(slot); ldB(slot);
    if (kt < 14){
      int ns = (kt+2)%3, kn = (kt+2)*32;
      stA(ns,kn); stB(ns,kn);
    }
    PRIO1;
    #pragma unroll
    for (int mr=0;mr<8;++mr)
      #pragma unroll
      for (int nj=0;nj<4;++nj)
        acc[mr][nj] = __builtin_amdgcn_mfma_f32_16x16x32_bf16(
            afr[mr], bfr[nj], acc[mr][nj], 0,0,0);
    PRIO0;
    if (kt < 14)       asm volatile("s_waitcnt vmcnt(6)" ::: "memory");
    else if (kt == 14) asm volatile("s_waitcnt vmcnt(0)" ::: "memory");
    SBAR; SCHED;
  }

  size_t cb = (size_t)z * 1536 * NS;
  #pragma unroll
  for (int mr=0;mr<8;++mr)
    #pragma unroll
    for (int nj=0;nj<4;++nj){
      int row = o0 + wm*128 + mr*16 + fg*4;
      int col = bn0 + wn*64 + nj*16 + fr;
      #pragma unroll
      for (int r=0;r<4;++r)
        Cm[cb + (size_t)(row+r)*NS + col] = f2bf(acc[mr][nj][r]);
    }
}

// ------ K6: full-column GEMM (512x128) + fused final ChanLN -> d_out -------
// r12 version (direct stores; r13's staged epilogue regressed).
__global__ __launch_bounds__(512, 2) void gemm2ln_k(const u16* __restrict__ A,
                                                    const u16* __restrict__ Bm,
                                                    const float* __restrict__ g2,
                                                    float* __restrict__ out){
  __shared__ u16 lds[3][20480];   // slot: A 256 lines (32KB), B 64 lines (8KB)
  int x = blockIdx.x, z = blockIdx.y;
  int n0 = x*128;
  int t = threadIdx.x;
  int lane = t & 63, wv = t >> 6;
  int wm = wv >> 1, wn = wv & 1;
  int fr = lane & 15, fg = lane >> 4;
  const u16* Ab = A;
  const u16* Bb = Bm + ((size_t)z*NS + n0)*512;

  int l8  = lane >> 3;
  int c8d = lane & 7;

  f32x4 acc[8][4];
  #pragma unroll
  for (int i=0;i<8;++i)
    #pragma unroll
    for (int j=0;j<4;++j) acc[i][j] = (f32x4){0.f,0.f,0.f,0.f};
  s16x8 afr[4], bfr[4];

  auto stA = [&](int slot, int kt, int bt){
    int L  = bt*64 + wv*8 + l8;
    int q  = c8d ^ (l8 & 7);
    int r  = (q >> 2)*256 + L;
    int col = kt + (q & 3)*8;
    gl_lds16(Ab + (size_t)r*512 + col, &lds[slot][(bt*64 + wv*8)*64]);
  };
  auto stB = [&](int slot, int kt){
    int L  = wv*8 + l8;
    int q  = c8d ^ (l8 & 7);
    int r  = (q >> 2)*64 + L;
    int col = kt + (q & 3)*8;
    gl_lds16(Bb + (size_t)r*512 + col, &lds[slot][16384 + (wv*8)*64]);
  };
  auto ldA = [&](int slot, int h){
    #pragma unroll
    for (int mi=0;mi<4;++mi){
      int R = wm*128 + (h*4+mi)*16 + fr;
      int L = R & 255, half = R >> 8;
      int c8 = (half*4 + fg) ^ (L & 7);
      afr[mi] = *(const s16x8*)&lds[slot][L*64 + c8*8];
    }
  };
  auto ldB = [&](int slot){
    #pragma unroll
    for (int nj=0;nj<4;++nj){
      int R = wn*64 + nj*16 + fr;
      int L = R & 63, half = R >> 6;
      int c8 = (half*4 + fg) ^ (L & 7);
      bfr[nj] = *(const s16x8*)&lds[slot][16384 + L*64 + c8*8];
    }
  };
  auto mm16 = [&](int h){
    #pragma unroll
    for (int mi=0;mi<4;++mi)
      #pragma unroll
      for (int nj=0;nj<4;++nj)
        acc[h*4+mi][nj] = __builtin_amdgcn_mfma_f32_16x16x32_bf16(
            afr[mi], bfr[nj], acc[h*4+mi][nj], 0,0,0);
  };

  #pragma unroll
  for (int p=0;p<2;++p){ stA(p,p*32,0); stA(p,p*32,1); stB(p,p*32); stA(p,p*32,2); stA(p,p*32,3); }
  asm volatile("s_waitcnt vmcnt(5)" ::: "memory");
  SBAR; SCHED;

  #pragma unroll
  for (int kt=0; kt<16; ++kt){
    int slot = kt%3;
    ldA(slot,0); ldB(slot);
    if (kt<14){
      int ns = (kt+2)%3, kn = (kt+2)*32;
      stA(ns,kn,0); stA(ns,kn,1); stB(ns,kn); stA(ns,kn,2); stA(ns,kn,3);
    }
    PRIO1; mm16(0); PRIO0;
    ldA(slot,1);
    PRIO1; mm16(1); PRIO0;
    if (kt<14)       asm volatile("s_waitcnt vmcnt(5)" ::: "memory");
    else if (kt==14) asm volatile("s_waitcnt vmcnt(0)" ::: "memory");
    SBAR; SCHED;
  }

  // ---- fused LN2: stats over all 512 rows per n-col, then write d_out ----
  __syncthreads();
  float* red1 = (float*)&lds[0][0];
  float* red2 = red1 + 512;
  float* ms   = red2 + 512;
  float* rs   = ms + 128;
  float s1[4], s2[4];
  #pragma unroll
  for (int nj=0;nj<4;++nj){
    float a = 0.f, b2 = 0.f;
    #pragma unroll
    for (int mi=0;mi<8;++mi)
      #pragma unroll
      for (int r=0;r<4;++r){ float v = acc[mi][nj][r]; a += v; b2 += v*v; }
    s1[nj] = a; s2[nj] = b2;
  }
  #pragma unroll
  for (int off=16; off<64; off<<=1)
    #pragma unroll
    for (int nj=0;nj<4;++nj){
      s1[nj] += __shfl_xor(s1[nj], off, 64);
      s2[nj] += __shfl_xor(s2[nj], off, 64);
    }
  if (fg == 0){
    #pragma unroll
    for (int nj=0;nj<4;++nj){
      int c = wn*64 + nj*16 + fr;
      red1[wm*128 + c] = s1[nj];
      red2[wm*128 + c] = s2[nj];
    }
  }
  __syncthreads();
  if (t < 128){
    float a  = red1[t] + red1[128+t] + red1[256+t] + red1[384+t];
    float b2 = red2[t] + red2[128+t] + red2[256+t] + red2[384+t];
    float mn = a * (1.f/512.f);
    float var = b2 * (1.f/512.f) - mn*mn;
    ms[t] = mn; rs[t] = rsqrtf(var + 1e-5f);
  }
  __syncthreads();
  float mc[4], rc[4];
  #pragma unroll
  for (int nj=0;nj<4;++nj){
    int c = wn*64 + nj*16 + fr;
    mc[nj] = ms[c]; rc[nj] = rs[c];
  }
  float* ob = out + (size_t)z*CD*NS + n0;
  #pragma unroll
  for (int mi=0;mi<8;++mi)
    #pragma unroll
    for (int r=0;r<4;++r){
      int row = wm*128 + mi*16 + fg*4 + r;
      float gg = g2[row];
      #pragma unroll
      for (int nj=0;nj<4;++nj)
        ob[(size_t)row*NS + wn*64 + nj*16 + fr] = (acc[mi][nj][r] - mc[nj])*rc[nj]*gg;
    }
}

// ------- K4: context partials (no-max k-softmax: |k| <= ~3, exp safe) ------
__global__ __launch_bounds__(256) void ctxpart_k(const u16* __restrict__ qkv,
                                                 float* __restrict__ part,
                                                 float* __restrict__ mS){
  int chunk = blockIdx.x, bh = blockIdx.y;
  int b = bh >> 3, h = bh & 7;
  int t = threadIdx.x;
  int lane = t & 63, wv = t >> 6;
  int fr = lane & 15, fg = lane >> 4;
  __shared__ u16 KT[64*128];
  __shared__ u16 VT[64*128];
  __shared__ float invn_s[128];
  const u16* kb = qkv + ((size_t)(b*1536 + 512  + h*64))*NS;
  const u16* vb = qkv + ((size_t)(b*1536 + 1024 + h*64))*NS;
  int d = t >> 2, q = t & 3;

  float sloc = 0.f;

  f32x4 acc[4][4];
  #pragma unroll
  for (int i=0;i<4;++i)
    #pragma unroll
    for (int j=0;j<4;++j) acc[i][j] = (f32x4){0.f,0.f,0.f,0.f};

  for (int nt = 0; nt < 4; ++nt){
    int n0 = chunk*512 + nt*128;
    if (nt) __syncthreads();
    u16x8 kreg[4];
    #pragma unroll
    for (int s = 0; s < 4; ++s){
      int c0 = q*32 + s*8;
      u16x8 vv = *(const u16x8*)&vb[(size_t)d*NS + n0 + c0];
      *(u16x8*)&VT[d*128 + (c0 ^ ((d&7)<<3))] = vv;
      kreg[s] = *(const u16x8*)&kb[(size_t)d*NS + n0 + c0];
    }
    __syncthreads();
    {
      int col = t >> 1, half = t & 1;
      float ss = 0.f;
      #pragma unroll
      for (int e2 = 0; e2 < 32; ++e2){
        int e = half*32 + e2;
        float xv = bf2f(VT[e*128 + (col ^ ((e&7)<<3))]);
        ss += xv*xv;
      }
      ss += __shfl_xor(ss, 1, 64);
      if (half == 0) invn_s[col] = rsqrtf(ss);
    }
    __syncthreads();
    #pragma unroll
    for (int s = 0; s < 4; ++s){
      int c0 = q*32 + s*8;
      u16x8 kk = kreg[s];
      u16x8 ek;
      #pragma unroll
      for (int j = 0; j < 8; ++j){
        float e = __expf(bf2f(kk[j]));
        sloc += e;
        ek[j] = f2bf(e * invn_s[c0 + j]);
      }
      *(u16x8*)&KT[d*128 + (c0 ^ ((d&7)<<3))] = ek;
    }
    __syncthreads();
    int kc = wv*32 + fg*8;
    s16x8 af[4], bfr[4];
    #pragma unroll
    for (int i=0;i<4;++i){
      int ra = i*16 + fr;
      af[i]  = *(const s16x8*)&KT[ra*128 + (kc ^ ((ra&7)<<3))];
      bfr[i] = *(const s16x8*)&VT[ra*128 + (kc ^ ((ra&7)<<3))];
    }
    #pragma unroll
    for (int i=0;i<4;++i)
      #pragma unroll
      for (int j=0;j<4;++j)
        acc[i][j] = __builtin_amdgcn_mfma_f32_16x16x32_bf16(af[i], bfr[j], acc[i][j], 0,0,0);
  }

  sloc += __shfl_xor(sloc, 1, 64);
  sloc += __shfl_xor(sloc, 2, 64);
  if (q == 0){
    size_t mb = ((size_t)bh*8 + chunk)*128;
    mS[mb + d]      = 0.0f;
    mS[mb + 64 + d] = sloc;
  }

  float* buf0 = (float*)KT;
  float* buf1 = (float*)VT;
  auto dump = [&](float* bf){
    #pragma unroll
    for (int i=0;i<4;++i)
      #pragma unroll
      for (int j=0;j<4;++j)
        #pragma unroll
        for (int r=0;r<4;++r) bf[((i*4+j)*4+r)*64 + lane] = acc[i][j][r];
  };
  auto addin = [&](float* bf){
    #pragma unroll
    for (int i=0;i<4;++i)
      #pragma unroll
      for (int j=0;j<4;++j)
        #pragma unroll
        for (int r=0;r<4;++r) acc[i][j][r] += bf[((i*4+j)*4+r)*64 + lane];
  };
  __syncthreads();
  if (wv==1) dump(buf0);
  if (wv==3) dump(buf1);
  __syncthreads();
  if (wv==0) addin(buf0);
  if (wv==2) addin(buf1);
  __syncthreads();
  if (wv==2) dump(buf0);
  __syncthreads();
  if (wv==0){
    addin(buf0);
    float* pp = part + ((size_t)bh*8 + chunk)*4096;
    #pragma unroll
    for (int i=0;i<4;++i)
      #pragma unroll
      for (int j=0;j<4;++j)
        #pragma unroll
        for (int r=0;r<4;++r)
          pp[(i*16+fg*4+r)*64 + j*16+fr] = acc[i][j][r];
  }
}

// ---- K4b: merge 8 chunk partials with online-softmax scales -> ctx --------
__global__ void ctxred_k(const float* __restrict__ part, const float* __restrict__ mS,
                         float* __restrict__ ctx){
  int bh = blockIdx.x, t = threadIdx.x;
  __shared__ float fs[8][64];
  if (t < 64){
    int d = t;
    float mc[8];
    float mx = -3.0e38f;
    #pragma unroll
    for (int c=0;c<8;++c){ mc[c] = mS[((size_t)bh*8 + c)*128 + d]; mx = fmaxf(mx, mc[c]); }
    float es[8]; float denom = 0.f;
    #pragma unroll
    for (int c=0;c<8;++c){
      es[c] = __expf(mc[c] - mx);
      denom += es[c] * mS[((size_t)bh*8 + c)*128 + 64 + d];
    }
    float inv = 1.0f / (denom * 4096.0f);
    #pragma unroll
    for (int c=0;c<8;++c) fs[c][d] = es[c] * inv;
  }
  __syncthreads();
  #pragma unroll
  for (int i=0;i<16;++i){
    int idx = t + i*256;
    int d = idx >> 6;
    float s = 0.f;
    #pragma unroll
    for (int ch=0; ch<8; ++ch) s += fs[ch][d] * part[((size_t)bh*8 + ch)*4096 + idx];
    ctx[(size_t)bh*4096 + idx] = s;
  }
}

// ------- K5: out = softmax_feat(q)*scale @ ctx  via MFMA, GELU, gT[b][n][c] -
__global__ __launch_bounds__(256) void attnout_k(const u16* __restrict__ qkv,
                                                 const float* __restrict__ ctx,
                                                 u16* __restrict__ gT){
  int bh = blockIdx.y;
  int b = bh >> 3, h = bh & 7;
  int n0 = blockIdx.x * 256;
  int t = threadIdx.x;
  int lane = t & 63, wv = t >> 6;
  int fr = lane & 15, fg = lane >> 4;
  __shared__ u16 P[256][72];
  __shared__ u16 cT[64][72];

  const float* cs = ctx + (size_t)bh*4096;
  #pragma unroll
  for (int i=0;i<16;++i){
    int idx = i*256 + t;
    int d = idx >> 6, e = idx & 63;
    cT[e][d] = f2bf(cs[idx]);
  }

  const u16* qb = qkv + ((size_t)(b*1536 + h*64))*NS + n0 + t;
  float p[64];
  #pragma unroll
  for (int d=0; d<64; ++d) p[d] = bf2f(qb[(size_t)d*NS]);
  float m = p[0];
  #pragma unroll
  for (int d=1; d<64; ++d) m = fmaxf(m, p[d]);
  float s = 0.f;
  #pragma unroll
  for (int d=0; d<64; ++d){ p[d] = __expf(p[d]-m); s += p[d]; }
  float inv = 0.125f / s;
  #pragma unroll
  for (int d0=0; d0<8; ++d0){
    u16x8 pk;
    #pragma unroll
    for (int j=0;j<8;++j) pk[j] = f2bf(p[d0*8+j] * inv);
    *(u16x8*)&P[t][d0*8] = pk;
  }
  __syncthreads();

  f32x4 acc[4][4];
  #pragma unroll
  for (int i=0;i<4;++i)
    #pragma unroll
    for (int j=0;j<4;++j) acc[i][j] = (f32x4){0.f,0.f,0.f,0.f};
  #pragma unroll
  for (int k=0; k<2; ++k){
    s16x8 af[4], bfr[4];
    #pragma unroll
    for (int i=0;i<4;++i){
      af[i]  = *(const s16x8*)&P[wv*64 + i*16 + fr][k*32 + fg*8];
      bfr[i] = *(const s16x8*)&cT[i*16 + fr][k*32 + fg*8];
    }
    #pragma unroll
    for (int i=0;i<4;++i)
      #pragma unroll
      for (int j=0;j<4;++j)
        acc[i][j] = __builtin_amdgcn_mfma_f32_16x16x32_bf16(af[i], bfr[j], acc[i][j], 0,0,0);
  }

  #pragma unroll
  for (int i=0;i<4;++i)
    #pragma unroll
    for (int j=0;j<4;++j)
      #pragma unroll
      for (int r=0;r<4;++r)
        P[wv*64 + i*16 + fg*4 + r][j*16 + fr] = f2bf(gelu_f(acc[i][j][r]));

  int sub = lane >> 4, e4 = (lane & 15) * 4;
  #pragma unroll
  for (int it=0; it<16; ++it){
    int row = wv*64 + it*4 + sub;
    *(u16x4*)&gT[((size_t)b*NS + n0 + row)*CD + h*64 + e4] = *(u16x4*)&P[row][e4];
  }
}

extern "C" void kernel_launch(void* const* d_in, const int* in_sizes, int n_in,
                              void* d_out, int out_size, void* d_ws, size_t ws_size,
                              hipStream_t stream) {
  const float* fmap = (const float*)d_in[0];
  const float* g1   = (const float*)d_in[1];
  const float* wqkv = (const float*)d_in[2];
  const float* wout = (const float*)d_in[3];
  const float* g2   = (const float*)d_in[4];
  float* out = (float*)d_out;

  char* ws = (char*)d_ws;
  size_t off = 0;
  auto alloc = [&](size_t bytes) -> void* {
    void* p = ws + off;
    off += (bytes + 255) & ~(size_t)255;
    return p;
  };
  u16*   qkv  = (u16*)alloc((size_t)16*1536*4096*2);
  u16*   xlnT = (u16*)alloc((size_t)16*4096*512*2);    // reused as gT
  u16*   gT   = xlnT;
  float* part = (float*)alloc((size_t)128*8*4096*4);
  float* mS   = (float*)alloc((size_t)128*8*128*4);
  float* ctx  = (float*)alloc((size_t)128*4096*4);
  u16*   w1b  = (u16*)alloc((size_t)1536*512*2);
  u16*   w2b  = (u16*)alloc((size_t)512*512*2);
  if (off > ws_size) return;

  prep_w_k<<<4096, 256, 0, stream>>>(wqkv, g1, wout, w1b, w2b);
  ln1t_k<<<dim3(128,16), 512, 0, stream>>>(fmap, xlnT);
  gemm1_k<<<3072, 256, 0, stream>>>(w1b, xlnT, qkv);
  ctxpart_k<<<dim3(8,128), 256, 0, stream>>>(qkv, part, mS);
  ctxred_k<<<128, 256, 0, stream>>>(part, mS, ctx);
  attnout_k<<<dim3(16,128), 256, 0, stream>>>(qkv, ctx, gT);
  gemm2ln_k<<<dim3(32,16), 512, 0, stream>>>(w2b, gT, g2, out);
}

// Round 15
// 314.527 us; speedup vs baseline: 1.0493x; 1.0437x over previous
//
#include <hip/hip_runtime.h>

typedef unsigned short u16;
typedef __attribute__((ext_vector_type(2))) float f32x2;
typedef __attribute__((ext_vector_type(4))) float f32x4;
typedef __attribute__((ext_vector_type(8))) short s16x8;
typedef __attribute__((ext_vector_type(8))) u16 u16x8;
typedef __attribute__((ext_vector_type(4))) u16 u16x4;

#define NB 16
#define CD 512
#define NS 4096
#define NHD 8

#define SBAR  __builtin_amdgcn_s_barrier()
#define SCHED __builtin_amdgcn_sched_barrier(0)
#define LGKM0 asm volatile("s_waitcnt lgkmcnt(0)" ::: "memory")
#define PRIO1 __builtin_amdgcn_s_setprio(1)
#define PRIO0 __builtin_amdgcn_s_setprio(0)

__device__ __forceinline__ float bf2f(u16 u){
  union { unsigned int i; float f; } z; z.i = ((unsigned int)u) << 16; return z.f;
}
__device__ __forceinline__ u16 f2bf(float f){
  union { float f; unsigned int i; } z; z.f = f;
  unsigned int i = z.i;
  return (u16)((i + 0x7fffu + ((i >> 16) & 1u)) >> 16);
}
__device__ __forceinline__ float gelu_f(float x){
  return 0.5f * x * (1.0f + erff(x * 0.70710678118654752440f));
}
__device__ __forceinline__ void gl_lds16(const u16* g, u16* l){
  __builtin_amdgcn_global_load_lds((const __attribute__((address_space(1))) void*)(g),
                                   (__attribute__((address_space(3))) void*)(l), 16, 0, 0);
}

// ---------------- K0: weights -> bf16 (g1 folded into w_qkv) ----------------
__global__ void prep_w_k(const float* __restrict__ wqkv, const float* __restrict__ g1,
                         const float* __restrict__ wout, u16* __restrict__ w1b,
                         u16* __restrict__ w2b){
  int i = blockIdx.x * 256 + threadIdx.x;
  if (i < 1536*512) {
    w1b[i] = f2bf(wqkv[i] * g1[i & 511]);
  } else {
    int j = i - 1536*512;
    w2b[j] = f2bf(wout[j]);
  }
}

// ------- K1: ChanLN over c, single global read, bf16 LDS staging -----------
// Stats computed from fp32 register values (exact); tile staged bf16
// (u16[512][40], ~41KB) -> LDS total ~49KB -> 3 blocks/CU (was 1 at fp32).
__global__ __launch_bounds__(512) void ln1t_k(const float* __restrict__ fmap,
                                              u16* __restrict__ xlnT){
  int b = blockIdx.y, n0 = blockIdx.x * 32;
  int t = threadIdx.x;
  int lane = t & 63, wv = t >> 6;
  __shared__ u16 Lb[512][40];
  __shared__ u16 Tt[64][36];
  __shared__ float red1[8][8][4], red2[8][8][4];
  __shared__ float mean_s[32], rstd_s[32];

  int ng = t & 7;
  float s1[4] = {0,0,0,0}, s2[4] = {0,0,0,0};
  const float* fb = fmap + ((size_t)b*CD)*NS + n0 + ng*4;
  #pragma unroll
  for (int it = 0; it < 8; ++it){
    int q = it*512 + t;
    int c = q >> 3;
    f32x4 v = *(const f32x4*)&fb[(size_t)c*NS];
    u16x4 pk;
    #pragma unroll
    for (int j = 0; j < 4; ++j){
      pk[j] = f2bf(v[j]);
      s1[j] += v[j]; s2[j] += v[j]*v[j];
    }
    *(u16x4*)&Lb[c][ng*4] = pk;
  }
  #pragma unroll
  for (int off = 8; off < 64; off <<= 1)
    #pragma unroll
    for (int j = 0; j < 4; ++j){
      s1[j] += __shfl_xor(s1[j], off, 64);
      s2[j] += __shfl_xor(s2[j], off, 64);
    }
  if (lane < 8){
    #pragma unroll
    for (int j = 0; j < 4; ++j){ red1[wv][lane][j] = s1[j]; red2[wv][lane][j] = s2[j]; }
  }
  __syncthreads();
  if (t < 32){
    int g = t >> 2, j = t & 3;
    float a = 0.f, bq = 0.f;
    #pragma unroll
    for (int w = 0; w < 8; ++w){ a += red1[w][g][j]; bq += red2[w][g][j]; }
    float mn = a * (1.f/512.f);
    float var = bq * (1.f/512.f) - mn*mn;
    mean_s[t] = mn; rstd_s[t] = rsqrtf(var + 1e-5f);
  }
  __syncthreads();

  for (int ct = 0; ct < 8; ++ct){
    {
      int cl = t >> 3, n4 = (t & 7) * 4;
      u16x4 xv = *(const u16x4*)&Lb[ct*64 + cl][n4];
      u16x4 pk;
      #pragma unroll
      for (int j = 0; j < 4; ++j)
        pk[j] = f2bf((bf2f(xv[j]) - mean_s[n4+j]) * rstd_s[n4+j]);
      *(u16x4*)&Tt[cl][n4] = pk;
    }
    __syncthreads();
    {
      int nr = t >> 4, c4 = t & 15;
      u16x4 w;
      #pragma unroll
      for (int j = 0; j < 4; ++j) w[j] = Tt[c4*4 + j][nr];
      *(u16x4*)&xlnT[((size_t)b*NS + n0 + nr)*CD + ct*64 + c4*4] = w;
    }
    __syncthreads();
  }
}

// ---------- K2: 256x256 GEMM, BK=64, lean 2-phase counted-vmcnt ------------
// EXACT r12 configuration (measured 115us, 0 conflicts, best of 9 variants).
__global__ __launch_bounds__(512) void gemm1_k(const u16* __restrict__ A,
                                               const u16* __restrict__ Bm,
                                               u16* __restrict__ Cm){
  __shared__ u16 lds[2][4][8192];   // [slot][Ah0,Ah1,Bh0,Bh1][128*64]
  int bi = blockIdx.x;
  int xcd = bi & 7, r2 = bi >> 3;
  int gi = r2 / 6, yy = r2 - gi*6;
  int g  = gi*8 + xcd;
  int x  = g & 15, z = g >> 4;
  int o0 = yy*256, bn0 = x*256;
  int t = threadIdx.x;
  int lane = t & 63, wv = t >> 6;
  int wm = wv >> 2, wn = wv & 3;
  int fr = lane & 15, fg = lane >> 4;
  const u16* Ab = A + (size_t)o0*512;
  const u16* Bb = Bm + ((size_t)z*NS + bn0)*512;
  int li8 = lane >> 3, scn = lane & 7;

  f32x4 acc[8][4];
  #pragma unroll
  for (int i=0;i<8;++i)
    #pragma unroll
    for (int j=0;j<4;++j) acc[i][j] = (f32x4){0.f,0.f,0.f,0.f};
  s16x8 afr[4][2];          // current A quadrant: 4 mr x 2 ks
  s16x8 bfr[2][2][2];       // both B quadrants kept: [nq][nr][ks]

  auto stH = [&](int slot, int half, int kt){   // one half-tile: 2 gl_lds
    #pragma unroll
    for (int it=0; it<2; ++it){
      int li = it*64 + wv*8 + li8;
      int q  = scn ^ (li & 7);                  // logical k-chunk (pre-swizzled src)
      int row;
      if (half < 2) row = ((li>>6)<<7) + half*64 + (li & 63);       // A
      else          row = ((li>>5)<<6) + (half-2)*32 + (li & 31);   // B
      const u16* G = (half < 2) ? Ab : Bb;
      gl_lds16(G + (size_t)row*512 + kt + q*8, &lds[slot][half][it*4096 + wv*512]);
    }
  };
  auto ldA = [&](int slot, int mq){
    #pragma unroll
    for (int mr=0;mr<4;++mr)
      #pragma unroll
      for (int ks=0;ks<2;++ks){
        int li = wm*64 + mr*16 + fr;
        int c8 = (ks*4+fg) ^ (li & 7);
        afr[mr][ks] = *(const s16x8*)&lds[slot][mq][li*64 + c8*8];
      }
  };
  auto ldB = [&](int slot, int nq){
    #pragma unroll
    for (int nr=0;nr<2;++nr)
      #pragma unroll
      for (int ks=0;ks<2;++ks){
        int li = wn*32 + nr*16 + fr;
        int c8 = (ks*4+fg) ^ (li & 7);
        bfr[nq][nr][ks] = *(const s16x8*)&lds[slot][2+nq][li*64 + c8*8];
      }
  };
  auto mm = [&](int mq, int nq){
    #pragma unroll
    for (int mr=0;mr<4;++mr)
      #pragma unroll
      for (int nr=0;nr<2;++nr)
        #pragma unroll
        for (int ks=0;ks<2;++ks)
          acc[mq*4+mr][nq*2+nr] = __builtin_amdgcn_mfma_f32_16x16x32_bf16(
              afr[mr][ks], bfr[nq][nr][ks], acc[mq*4+mr][nq*2+nr], 0,0,0);
  };

  // prologue: tile 0, halves in consumption order Ah0,Bh0,Bh1,Ah1
  stH(0,0,0); stH(0,2,0); stH(0,3,0); stH(0,1,0);
  asm volatile("s_waitcnt vmcnt(2)" ::: "memory");   // first 3 halves landed
  SBAR; SCHED;

  #pragma unroll
  for (int kt=0; kt<8; ++kt){
    int slot = kt & 1, ns = slot ^ 1, kn = (kt+1)*64;
    bool F = kt < 7;
    // P1: quads (m0,n0) + (m0,n1)
    ldA(slot,0); ldB(slot,0); ldB(slot,1);
    if (F){ stH(ns,0,kn); stH(ns,2,kn); stH(ns,3,kn); }
    PRIO1; mm(0,0); mm(0,1); PRIO0;
    if (F) asm volatile("s_waitcnt vmcnt(6)" ::: "memory");   // prev P2's Ah1 done
    else   asm volatile("s_waitcnt vmcnt(0)" ::: "memory");
    SBAR; SCHED;
    // P2: quads (m1,n1) + (m1,n0)
    ldA(slot,1);
    if (F) stH(ns,1,kn);
    PRIO1; mm(1,1); mm(1,0); PRIO0;
    if (F) asm volatile("s_waitcnt vmcnt(2)" ::: "memory");   // P1's 3 halves done
    SBAR; SCHED;
  }

  size_t cb = (size_t)z * 1536 * NS;
  #pragma unroll
  for (int mq=0;mq<2;++mq)
    #pragma unroll
    for (int mr=0;mr<4;++mr)
      #pragma unroll
      for (int nq=0;nq<2;++nq)
        #pragma unroll
        for (int nr=0;nr<2;++nr){
          int row = o0 + wm*128 + mq*64 + mr*16 + fg*4;
          int col = bn0 + wn*64 + nq*32 + nr*16 + fr;
          #pragma unroll
          for (int r=0;r<4;++r)
            Cm[cb + (size_t)(row+r)*NS + col] = f2bf(acc[mq*4+mr][nq*2+nr][r]);
        }
}

// ------ K6: full-column GEMM (512x128) + fused final ChanLN -> d_out -------
__global__ __launch_bounds__(512, 2) void gemm2ln_k(const u16* __restrict__ A,
                                                    const u16* __restrict__ Bm,
                                                    const float* __restrict__ g2,
                                                    float* __restrict__ out){
  __shared__ u16 lds[3][20480];   // slot: A 256 lines (32KB), B 64 lines (8KB)
  int x = blockIdx.x, z = blockIdx.y;
  int n0 = x*128;
  int t = threadIdx.x;
  int lane = t & 63, wv = t >> 6;
  int wm = wv >> 1, wn = wv & 1;
  int fr = lane & 15, fg = lane >> 4;
  const u16* Ab = A;
  const u16* Bb = Bm + ((size_t)z*NS + n0)*512;

  int l8  = lane >> 3;
  int c8d = lane & 7;

  f32x4 acc[8][4];
  #pragma unroll
  for (int i=0;i<8;++i)
    #pragma unroll
    for (int j=0;j<4;++j) acc[i][j] = (f32x4){0.f,0.f,0.f,0.f};
  s16x8 afr[4], bfr[4];

  auto stA = [&](int slot, int kt, int bt){
    int L  = bt*64 + wv*8 + l8;
    int q  = c8d ^ (l8 & 7);
    int r  = (q >> 2)*256 + L;
    int col = kt + (q & 3)*8;
    gl_lds16(Ab + (size_t)r*512 + col, &lds[slot][(bt*64 + wv*8)*64]);
  };
  auto stB = [&](int slot, int kt){
    int L  = wv*8 + l8;
    int q  = c8d ^ (l8 & 7);
    int r  = (q >> 2)*64 + L;
    int col = kt + (q & 3)*8;
    gl_lds16(Bb + (size_t)r*512 + col, &lds[slot][16384 + (wv*8)*64]);
  };
  auto ldA = [&](int slot, int h){
    #pragma unroll
    for (int mi=0;mi<4;++mi){
      int R = wm*128 + (h*4+mi)*16 + fr;
      int L = R & 255, half = R >> 8;
      int c8 = (half*4 + fg) ^ (L & 7);
      afr[mi] = *(const s16x8*)&lds[slot][L*64 + c8*8];
    }
  };
  auto ldB = [&](int slot){
    #pragma unroll
    for (int nj=0;nj<4;++nj){
      int R = wn*64 + nj*16 + fr;
      int L = R & 63, half = R >> 6;
      int c8 = (half*4 + fg) ^ (L & 7);
      bfr[nj] = *(const s16x8*)&lds[slot][16384 + L*64 + c8*8];
    }
  };
  auto mm16 = [&](int h){
    #pragma unroll
    for (int mi=0;mi<4;++mi)
      #pragma unroll
      for (int nj=0;nj<4;++nj)
        acc[h*4+mi][nj] = __builtin_amdgcn_mfma_f32_16x16x32_bf16(
            afr[mi], bfr[nj], acc[h*4+mi][nj], 0,0,0);
  };

  #pragma unroll
  for (int p=0;p<2;++p){ stA(p,p*32,0); stA(p,p*32,1); stB(p,p*32); stA(p,p*32,2); stA(p,p*32,3); }
  asm volatile("s_waitcnt vmcnt(5)" ::: "memory");
  SBAR; SCHED;

  #pragma unroll
  for (int kt=0; kt<16; ++kt){
    int slot = kt%3;
    ldA(slot,0); ldB(slot);
    if (kt<14){
      int ns = (kt+2)%3, kn = (kt+2)*32;
      stA(ns,kn,0); stA(ns,kn,1); stB(ns,kn); stA(ns,kn,2); stA(ns,kn,3);
    }
    PRIO1; mm16(0); PRIO0;
    ldA(slot,1);
    PRIO1; mm16(1); PRIO0;
    if (kt<14)       asm volatile("s_waitcnt vmcnt(5)" ::: "memory");
    else if (kt==14) asm volatile("s_waitcnt vmcnt(0)" ::: "memory");
    SBAR; SCHED;
  }

  // ---- fused LN2: stats over all 512 rows per n-col, then write d_out ----
  __syncthreads();
  float* red1 = (float*)&lds[0][0];
  float* red2 = red1 + 512;
  float* ms   = red2 + 512;
  float* rs   = ms + 128;
  float s1[4], s2[4];
  #pragma unroll
  for (int nj=0;nj<4;++nj){
    float a = 0.f, b2 = 0.f;
    #pragma unroll
    for (int mi=0;mi<8;++mi)
      #pragma unroll
      for (int r=0;r<4;++r){ float v = acc[mi][nj][r]; a += v; b2 += v*v; }
    s1[nj] = a; s2[nj] = b2;
  }
  #pragma unroll
  for (int off=16; off<64; off<<=1)
    #pragma unroll
    for (int nj=0;nj<4;++nj){
      s1[nj] += __shfl_xor(s1[nj], off, 64);
      s2[nj] += __shfl_xor(s2[nj], off, 64);
    }
  if (fg == 0){
    #pragma unroll
    for (int nj=0;nj<4;++nj){
      int c = wn*64 + nj*16 + fr;
      red1[wm*128 + c] = s1[nj];
      red2[wm*128 + c] = s2[nj];
    }
  }
  __syncthreads();
  if (t < 128){
    float a  = red1[t] + red1[128+t] + red1[256+t] + red1[384+t];
    float b2 = red2[t] + red2[128+t] + red2[256+t] + red2[384+t];
    float mn = a * (1.f/512.f);
    float var = b2 * (1.f/512.f) - mn*mn;
    ms[t] = mn; rs[t] = rsqrtf(var + 1e-5f);
  }
  __syncthreads();
  float mc[4], rc[4];
  #pragma unroll
  for (int nj=0;nj<4;++nj){
    int c = wn*64 + nj*16 + fr;
    mc[nj] = ms[c]; rc[nj] = rs[c];
  }
  float* ob = out + (size_t)z*CD*NS + n0;
  #pragma unroll
  for (int mi=0;mi<8;++mi)
    #pragma unroll
    for (int r=0;r<4;++r){
      int row = wm*128 + mi*16 + fg*4 + r;
      float gg = g2[row];
      #pragma unroll
      for (int nj=0;nj<4;++nj)
        ob[(size_t)row*NS + wn*64 + nj*16 + fr] = (acc[mi][nj][r] - mc[nj])*rc[nj]*gg;
    }
}

// ------- K4: context partials (no-max k-softmax: |k| <= ~3, exp safe) ------
__global__ __launch_bounds__(256) void ctxpart_k(const u16* __restrict__ qkv,
                                                 float* __restrict__ part,
                                                 float* __restrict__ mS){
  int chunk = blockIdx.x, bh = blockIdx.y;
  int b = bh >> 3, h = bh & 7;
  int t = threadIdx.x;
  int lane = t & 63, wv = t >> 6;
  int fr = lane & 15, fg = lane >> 4;
  __shared__ u16 KT[64*128];
  __shared__ u16 VT[64*128];
  __shared__ float invn_s[128];
  const u16* kb = qkv + ((size_t)(b*1536 + 512  + h*64))*NS;
  const u16* vb = qkv + ((size_t)(b*1536 + 1024 + h*64))*NS;
  int d = t >> 2, q = t & 3;

  float sloc = 0.f;

  f32x4 acc[4][4];
  #pragma unroll
  for (int i=0;i<4;++i)
    #pragma unroll
    for (int j=0;j<4;++j) acc[i][j] = (f32x4){0.f,0.f,0.f,0.f};

  for (int nt = 0; nt < 4; ++nt){
    int n0 = chunk*512 + nt*128;
    if (nt) __syncthreads();
    u16x8 kreg[4];
    #pragma unroll
    for (int s = 0; s < 4; ++s){
      int c0 = q*32 + s*8;
      u16x8 vv = *(const u16x8*)&vb[(size_t)d*NS + n0 + c0];
      *(u16x8*)&VT[d*128 + (c0 ^ ((d&7)<<3))] = vv;
      kreg[s] = *(const u16x8*)&kb[(size_t)d*NS + n0 + c0];
    }
    __syncthreads();
    {
      int col = t >> 1, half = t & 1;
      float ss = 0.f;
      #pragma unroll
      for (int e2 = 0; e2 < 32; ++e2){
        int e = half*32 + e2;
        float xv = bf2f(VT[e*128 + (col ^ ((e&7)<<3))]);
        ss += xv*xv;
      }
      ss += __shfl_xor(ss, 1, 64);
      if (half == 0) invn_s[col] = rsqrtf(ss);
    }
    __syncthreads();
    #pragma unroll
    for (int s = 0; s < 4; ++s){
      int c0 = q*32 + s*8;
      u16x8 kk = kreg[s];
      u16x8 ek;
      #pragma unroll
      for (int j = 0; j < 8; ++j){
        float e = __expf(bf2f(kk[j]));
        sloc += e;
        ek[j] = f2bf(e * invn_s[c0 + j]);
      }
      *(u16x8*)&KT[d*128 + (c0 ^ ((d&7)<<3))] = ek;
    }
    __syncthreads();
    int kc = wv*32 + fg*8;
    s16x8 af[4], bfr[4];
    #pragma unroll
    for (int i=0;i<4;++i){
      int ra = i*16 + fr;
      af[i]  = *(const s16x8*)&KT[ra*128 + (kc ^ ((ra&7)<<3))];
      bfr[i] = *(const s16x8*)&VT[ra*128 + (kc ^ ((ra&7)<<3))];
    }
    #pragma unroll
    for (int i=0;i<4;++i)
      #pragma unroll
      for (int j=0;j<4;++j)
        acc[i][j] = __builtin_amdgcn_mfma_f32_16x16x32_bf16(af[i], bfr[j], acc[i][j], 0,0,0);
  }

  sloc += __shfl_xor(sloc, 1, 64);
  sloc += __shfl_xor(sloc, 2, 64);
  if (q == 0){
    size_t mb = ((size_t)bh*8 + chunk)*128;
    mS[mb + d]      = 0.0f;
    mS[mb + 64 + d] = sloc;
  }

  float* buf0 = (float*)KT;
  float* buf1 = (float*)VT;
  auto dump = [&](float* bf){
    #pragma unroll
    for (int i=0;i<4;++i)
      #pragma unroll
      for (int j=0;j<4;++j)
        #pragma unroll
        for (int r=0;r<4;++r) bf[((i*4+j)*4+r)*64 + lane] = acc[i][j][r];
  };
  auto addin = [&](float* bf){
    #pragma unroll
    for (int i=0;i<4;++i)
      #pragma unroll
      for (int j=0;j<4;++j)
        #pragma unroll
        for (int r=0;r<4;++r) acc[i][j][r] += bf[((i*4+j)*4+r)*64 + lane];
  };
  __syncthreads();
  if (wv==1) dump(buf0);
  if (wv==3) dump(buf1);
  __syncthreads();
  if (wv==0) addin(buf0);
  if (wv==2) addin(buf1);
  __syncthreads();
  if (wv==2) dump(buf0);
  __syncthreads();
  if (wv==0){
    addin(buf0);
    float* pp = part + ((size_t)bh*8 + chunk)*4096;
    #pragma unroll
    for (int i=0;i<4;++i)
      #pragma unroll
      for (int j=0;j<4;++j)
        #pragma unroll
        for (int r=0;r<4;++r)
          pp[(i*16+fg*4+r)*64 + j*16+fr] = acc[i][j][r];
  }
}

// ---- K4b: merge 8 chunk partials with online-softmax scales -> ctx --------
__global__ void ctxred_k(const float* __restrict__ part, const float* __restrict__ mS,
                         float* __restrict__ ctx){
  int bh = blockIdx.x, t = threadIdx.x;
  __shared__ float fs[8][64];
  if (t < 64){
    int d = t;
    float mc[8];
    float mx = -3.0e38f;
    #pragma unroll
    for (int c=0;c<8;++c){ mc[c] = mS[((size_t)bh*8 + c)*128 + d]; mx = fmaxf(mx, mc[c]); }
    float es[8]; float denom = 0.f;
    #pragma unroll
    for (int c=0;c<8;++c){
      es[c] = __expf(mc[c] - mx);
      denom += es[c] * mS[((size_t)bh*8 + c)*128 + 64 + d];
    }
    float inv = 1.0f / (denom * 4096.0f);
    #pragma unroll
    for (int c=0;c<8;++c) fs[c][d] = es[c] * inv;
  }
  __syncthreads();
  #pragma unroll
  for (int i=0;i<16;++i){
    int idx = t + i*256;
    int d = idx >> 6;
    float s = 0.f;
    #pragma unroll
    for (int ch=0; ch<8; ++ch) s += fs[ch][d] * part[((size_t)bh*8 + ch)*4096 + idx];
    ctx[(size_t)bh*4096 + idx] = s;
  }
}

// ------- K5: out = softmax_feat(q)*scale @ ctx  via MFMA, GELU, gT[b][n][c] -
__global__ __launch_bounds__(256) void attnout_k(const u16* __restrict__ qkv,
                                                 const float* __restrict__ ctx,
                                                 u16* __restrict__ gT){
  int bh = blockIdx.y;
  int b = bh >> 3, h = bh & 7;
  int n0 = blockIdx.x * 256;
  int t = threadIdx.x;
  int lane = t & 63, wv = t >> 6;
  int fr = lane & 15, fg = lane >> 4;
  __shared__ u16 P[256][72];
  __shared__ u16 cT[64][72];

  const float* cs = ctx + (size_t)bh*4096;
  #pragma unroll
  for (int i=0;i<16;++i){
    int idx = i*256 + t;
    int d = idx >> 6, e = idx & 63;
    cT[e][d] = f2bf(cs[idx]);
  }

  const u16* qb = qkv + ((size_t)(b*1536 + h*64))*NS + n0 + t;
  float p[64];
  #pragma unroll
  for (int d=0; d<64; ++d) p[d] = bf2f(qb[(size_t)d*NS]);
  float m = p[0];
  #pragma unroll
  for (int d=1; d<64; ++d) m = fmaxf(m, p[d]);
  float s = 0.f;
  #pragma unroll
  for (int d=0; d<64; ++d){ p[d] = __expf(p[d]-m); s += p[d]; }
  float inv = 0.125f / s;
  #pragma unroll
  for (int d0=0; d0<8; ++d0){
    u16x8 pk;
    #pragma unroll
    for (int j=0;j<8;++j) pk[j] = f2bf(p[d0*8+j] * inv);
    *(u16x8*)&P[t][d0*8] = pk;
  }
  __syncthreads();

  f32x4 acc[4][4];
  #pragma unroll
  for (int i=0;i<4;++i)
    #pragma unroll
    for (int j=0;j<4;++j) acc[i][j] = (f32x4){0.f,0.f,0.f,0.f};
  #pragma unroll
  for (int k=0; k<2; ++k){
    s16x8 af[4], bfr[4];
    #pragma unroll
    for (int i=0;i<4;++i){
      af[i]  = *(const s16x8*)&P[wv*64 + i*16 + fr][k*32 + fg*8];
      bfr[i] = *(const s16x8*)&cT[i*16 + fr][k*32 + fg*8];
    }
    #pragma unroll
    for (int i=0;i<4;++i)
      #pragma unroll
      for (int j=0;j<4;++j)
        acc[i][j] = __builtin_amdgcn_mfma_f32_16x16x32_bf16(af[i], bfr[j], acc[i][j], 0,0,0);
  }

  #pragma unroll
  for (int i=0;i<4;++i)
    #pragma unroll
    for (int j=0;j<4;++j)
      #pragma unroll
      for (int r=0;r<4;++r)
        P[wv*64 + i*16 + fg*4 + r][j*16 + fr] = f2bf(gelu_f(acc[i][j][r]));

  int sub = lane >> 4, e4 = (lane & 15) * 4;
  #pragma unroll
  for (int it=0; it<16; ++it){
    int row = wv*64 + it*4 + sub;
    *(u16x4*)&gT[((size_t)b*NS + n0 + row)*CD + h*64 + e4] = *(u16x4*)&P[row][e4];
  }
}

extern "C" void kernel_launch(void* const* d_in, const int* in_sizes, int n_in,
                              void* d_out, int out_size, void* d_ws, size_t ws_size,
                              hipStream_t stream) {
  const float* fmap = (const float*)d_in[0];
  const float* g1   = (const float*)d_in[1];
  const float* wqkv = (const float*)d_in[2];
  const float* wout = (const float*)d_in[3];
  const float* g2   = (const float*)d_in[4];
  float* out = (float*)d_out;

  char* ws = (char*)d_ws;
  size_t off = 0;
  auto alloc = [&](size_t bytes) -> void* {
    void* p = ws + off;
    off += (bytes + 255) & ~(size_t)255;
    return p;
  };
  u16*   qkv  = (u16*)alloc((size_t)16*1536*4096*2);
  u16*   xlnT = (u16*)alloc((size_t)16*4096*512*2);    // reused as gT
  u16*   gT   = xlnT;
  float* part = (float*)alloc((size_t)128*8*4096*4);
  float* mS   = (float*)alloc((size_t)128*8*128*4);
  float* ctx  = (float*)alloc((size_t)128*4096*4);
  u16*   w1b  = (u16*)alloc((size_t)1536*512*2);
  u16*   w2b  = (u16*)alloc((size_t)512*512*2);
  if (off > ws_size) return;

  prep_w_k<<<4096, 256, 0, stream>>>(wqkv, g1, wout, w1b, w2b);
  ln1t_k<<<dim3(128,16), 512, 0, stream>>>(fmap, xlnT);
  gemm1_k<<<1536, 512, 0, stream>>>(w1b, xlnT, qkv);
  ctxpart_k<<<dim3(8,128), 256, 0, stream>>>(qkv, part, mS);
  ctxred_k<<<128, 256, 0, stream>>>(part, mS, ctx);
  attnout_k<<<dim3(16,128), 256, 0, stream>>>(qkv, ctx, gT);
  gemm2ln_k<<<dim3(32,16), 512, 0, stream>>>(w2b, gT, g2, out);
}

// Round 16
// 314.422 us; speedup vs baseline: 1.0496x; 1.0003x over previous
//
#include <hip/hip_runtime.h>

typedef unsigned short u16;
typedef __attribute__((ext_vector_type(2))) float f32x2;
typedef __attribute__((ext_vector_type(4))) float f32x4;
typedef __attribute__((ext_vector_type(8))) short s16x8;
typedef __attribute__((ext_vector_type(8))) u16 u16x8;
typedef __attribute__((ext_vector_type(4))) u16 u16x4;

#define NB 16
#define CD 512
#define NS 4096
#define NHD 8

#define SBAR  __builtin_amdgcn_s_barrier()
#define SCHED __builtin_amdgcn_sched_barrier(0)
#define LGKM0 asm volatile("s_waitcnt lgkmcnt(0)" ::: "memory")
#define PRIO1 __builtin_amdgcn_s_setprio(1)
#define PRIO0 __builtin_amdgcn_s_setprio(0)

__device__ __forceinline__ float bf2f(u16 u){
  union { unsigned int i; float f; } z; z.i = ((unsigned int)u) << 16; return z.f;
}
__device__ __forceinline__ u16 f2bf(float f){
  union { float f; unsigned int i; } z; z.f = f;
  unsigned int i = z.i;
  return (u16)((i + 0x7fffu + ((i >> 16) & 1u)) >> 16);
}
__device__ __forceinline__ float gelu_f(float x){
  return 0.5f * x * (1.0f + erff(x * 0.70710678118654752440f));
}
__device__ __forceinline__ void gl_lds16(const u16* g, u16* l){
  __builtin_amdgcn_global_load_lds((const __attribute__((address_space(1))) void*)(g),
                                   (__attribute__((address_space(3))) void*)(l), 16, 0, 0);
}

// ---------------- K0: weights -> bf16 (g1 folded into w_qkv) ----------------
__global__ void prep_w_k(const float* __restrict__ wqkv, const float* __restrict__ g1,
                         const float* __restrict__ wout, u16* __restrict__ w1b,
                         u16* __restrict__ w2b){
  int i = blockIdx.x * 256 + threadIdx.x;
  if (i < 1536*512) {
    w1b[i] = f2bf(wqkv[i] * g1[i & 511]);
  } else {
    int j = i - 1536*512;
    w2b[j] = f2bf(wout[j]);
  }
}

// ------- K1: ChanLN over c, single global read, bf16 LDS staging -----------
__global__ __launch_bounds__(512) void ln1t_k(const float* __restrict__ fmap,
                                              u16* __restrict__ xlnT){
  int b = blockIdx.y, n0 = blockIdx.x * 32;
  int t = threadIdx.x;
  int lane = t & 63, wv = t >> 6;
  __shared__ u16 Lb[512][40];
  __shared__ u16 Tt[64][36];
  __shared__ float red1[8][8][4], red2[8][8][4];
  __shared__ float mean_s[32], rstd_s[32];

  int ng = t & 7;
  float s1[4] = {0,0,0,0}, s2[4] = {0,0,0,0};
  const float* fb = fmap + ((size_t)b*CD)*NS + n0 + ng*4;
  #pragma unroll
  for (int it = 0; it < 8; ++it){
    int q = it*512 + t;
    int c = q >> 3;
    f32x4 v = *(const f32x4*)&fb[(size_t)c*NS];
    u16x4 pk;
    #pragma unroll
    for (int j = 0; j < 4; ++j){
      pk[j] = f2bf(v[j]);
      s1[j] += v[j]; s2[j] += v[j]*v[j];
    }
    *(u16x4*)&Lb[c][ng*4] = pk;
  }
  #pragma unroll
  for (int off = 8; off < 64; off <<= 1)
    #pragma unroll
    for (int j = 0; j < 4; ++j){
      s1[j] += __shfl_xor(s1[j], off, 64);
      s2[j] += __shfl_xor(s2[j], off, 64);
    }
  if (lane < 8){
    #pragma unroll
    for (int j = 0; j < 4; ++j){ red1[wv][lane][j] = s1[j]; red2[wv][lane][j] = s2[j]; }
  }
  __syncthreads();
  if (t < 32){
    int g = t >> 2, j = t & 3;
    float a = 0.f, bq = 0.f;
    #pragma unroll
    for (int w = 0; w < 8; ++w){ a += red1[w][g][j]; bq += red2[w][g][j]; }
    float mn = a * (1.f/512.f);
    float var = bq * (1.f/512.f) - mn*mn;
    mean_s[t] = mn; rstd_s[t] = rsqrtf(var + 1e-5f);
  }
  __syncthreads();

  for (int ct = 0; ct < 8; ++ct){
    {
      int cl = t >> 3, n4 = (t & 7) * 4;
      u16x4 xv = *(const u16x4*)&Lb[ct*64 + cl][n4];
      u16x4 pk;
      #pragma unroll
      for (int j = 0; j < 4; ++j)
        pk[j] = f2bf((bf2f(xv[j]) - mean_s[n4+j]) * rstd_s[n4+j]);
      *(u16x4*)&Tt[cl][n4] = pk;
    }
    __syncthreads();
    {
      int nr = t >> 4, c4 = t & 15;
      u16x4 w;
      #pragma unroll
      for (int j = 0; j < 4; ++j) w[j] = Tt[c4*4 + j][nr];
      *(u16x4*)&xlnT[((size_t)b*NS + n0 + nr)*CD + ct*64 + c4*4] = w;
    }
    __syncthreads();
  }
}

// ---------- K2: 256x256 GEMM, BK=64, lean 2-phase counted-vmcnt ------------
// EXACT r12 configuration (measured 115us, 0 conflicts, best of 9 variants).
__global__ __launch_bounds__(512) void gemm1_k(const u16* __restrict__ A,
                                               const u16* __restrict__ Bm,
                                               u16* __restrict__ Cm){
  __shared__ u16 lds[2][4][8192];   // [slot][Ah0,Ah1,Bh0,Bh1][128*64]
  int bi = blockIdx.x;
  int xcd = bi & 7, r2 = bi >> 3;
  int gi = r2 / 6, yy = r2 - gi*6;
  int g  = gi*8 + xcd;
  int x  = g & 15, z = g >> 4;
  int o0 = yy*256, bn0 = x*256;
  int t = threadIdx.x;
  int lane = t & 63, wv = t >> 6;
  int wm = wv >> 2, wn = wv & 3;
  int fr = lane & 15, fg = lane >> 4;
  const u16* Ab = A + (size_t)o0*512;
  const u16* Bb = Bm + ((size_t)z*NS + bn0)*512;
  int li8 = lane >> 3, scn = lane & 7;

  f32x4 acc[8][4];
  #pragma unroll
  for (int i=0;i<8;++i)
    #pragma unroll
    for (int j=0;j<4;++j) acc[i][j] = (f32x4){0.f,0.f,0.f,0.f};
  s16x8 afr[4][2];          // current A quadrant: 4 mr x 2 ks
  s16x8 bfr[2][2][2];       // both B quadrants kept: [nq][nr][ks]

  auto stH = [&](int slot, int half, int kt){   // one half-tile: 2 gl_lds
    #pragma unroll
    for (int it=0; it<2; ++it){
      int li = it*64 + wv*8 + li8;
      int q  = scn ^ (li & 7);                  // logical k-chunk (pre-swizzled src)
      int row;
      if (half < 2) row = ((li>>6)<<7) + half*64 + (li & 63);       // A
      else          row = ((li>>5)<<6) + (half-2)*32 + (li & 31);   // B
      const u16* G = (half < 2) ? Ab : Bb;
      gl_lds16(G + (size_t)row*512 + kt + q*8, &lds[slot][half][it*4096 + wv*512]);
    }
  };
  auto ldA = [&](int slot, int mq){
    #pragma unroll
    for (int mr=0;mr<4;++mr)
      #pragma unroll
      for (int ks=0;ks<2;++ks){
        int li = wm*64 + mr*16 + fr;
        int c8 = (ks*4+fg) ^ (li & 7);
        afr[mr][ks] = *(const s16x8*)&lds[slot][mq][li*64 + c8*8];
      }
  };
  auto ldB = [&](int slot, int nq){
    #pragma unroll
    for (int nr=0;nr<2;++nr)
      #pragma unroll
      for (int ks=0;ks<2;++ks){
        int li = wn*32 + nr*16 + fr;
        int c8 = (ks*4+fg) ^ (li & 7);
        bfr[nq][nr][ks] = *(const s16x8*)&lds[slot][2+nq][li*64 + c8*8];
      }
  };
  auto mm = [&](int mq, int nq){
    #pragma unroll
    for (int mr=0;mr<4;++mr)
      #pragma unroll
      for (int nr=0;nr<2;++nr)
        #pragma unroll
        for (int ks=0;ks<2;++ks)
          acc[mq*4+mr][nq*2+nr] = __builtin_amdgcn_mfma_f32_16x16x32_bf16(
              afr[mr][ks], bfr[nq][nr][ks], acc[mq*4+mr][nq*2+nr], 0,0,0);
  };

  // prologue: tile 0, halves in consumption order Ah0,Bh0,Bh1,Ah1
  stH(0,0,0); stH(0,2,0); stH(0,3,0); stH(0,1,0);
  asm volatile("s_waitcnt vmcnt(2)" ::: "memory");   // first 3 halves landed
  SBAR; SCHED;

  #pragma unroll
  for (int kt=0; kt<8; ++kt){
    int slot = kt & 1, ns = slot ^ 1, kn = (kt+1)*64;
    bool F = kt < 7;
    // P1: quads (m0,n0) + (m0,n1)
    ldA(slot,0); ldB(slot,0); ldB(slot,1);
    if (F){ stH(ns,0,kn); stH(ns,2,kn); stH(ns,3,kn); }
    PRIO1; mm(0,0); mm(0,1); PRIO0;
    if (F) asm volatile("s_waitcnt vmcnt(6)" ::: "memory");   // prev P2's Ah1 done
    else   asm volatile("s_waitcnt vmcnt(0)" ::: "memory");
    SBAR; SCHED;
    // P2: quads (m1,n1) + (m1,n0)
    ldA(slot,1);
    if (F) stH(ns,1,kn);
    PRIO1; mm(1,1); mm(1,0); PRIO0;
    if (F) asm volatile("s_waitcnt vmcnt(2)" ::: "memory");   // P1's 3 halves done
    SBAR; SCHED;
  }

  size_t cb = (size_t)z * 1536 * NS;
  #pragma unroll
  for (int mq=0;mq<2;++mq)
    #pragma unroll
    for (int mr=0;mr<4;++mr)
      #pragma unroll
      for (int nq=0;nq<2;++nq)
        #pragma unroll
        for (int nr=0;nr<2;++nr){
          int row = o0 + wm*128 + mq*64 + mr*16 + fg*4;
          int col = bn0 + wn*64 + nq*32 + nr*16 + fr;
          #pragma unroll
          for (int r=0;r<4;++r)
            Cm[cb + (size_t)(row+r)*NS + col] = f2bf(acc[mq*4+mr][nq*2+nr][r]);
        }
}

// ------ K6: full-column GEMM (512x128) + fused final ChanLN -> d_out -------
// 2-slot ring (80KB LDS -> 2 blocks/CU, 16 waves): big per-wave tile
// (128x64) AND cross-block overlap. Stage tile t+1 at top of kt (one full
// compute phase of flight); vmcnt(0) gate at kt end (required w/ 2 slots;
// stall absorbed by co-resident block).
__global__ __launch_bounds__(512, 2) void gemm2ln_k(const u16* __restrict__ A,
                                                    const u16* __restrict__ Bm,
                                                    const float* __restrict__ g2,
                                                    float* __restrict__ out){
  __shared__ u16 lds[2][20480];   // slot: A 256 lines (32KB), B 64 lines (8KB)
  int x = blockIdx.x, z = blockIdx.y;
  int n0 = x*128;
  int t = threadIdx.x;
  int lane = t & 63, wv = t >> 6;
  int wm = wv >> 1, wn = wv & 1;
  int fr = lane & 15, fg = lane >> 4;
  const u16* Ab = A;
  const u16* Bb = Bm + ((size_t)z*NS + n0)*512;

  int l8  = lane >> 3;
  int c8d = lane & 7;

  f32x4 acc[8][4];
  #pragma unroll
  for (int i=0;i<8;++i)
    #pragma unroll
    for (int j=0;j<4;++j) acc[i][j] = (f32x4){0.f,0.f,0.f,0.f};
  s16x8 afr[4], bfr[4];

  auto stA = [&](int slot, int kt, int bt){
    int L  = bt*64 + wv*8 + l8;
    int q  = c8d ^ (l8 & 7);
    int r  = (q >> 2)*256 + L;
    int col = kt + (q & 3)*8;
    gl_lds16(Ab + (size_t)r*512 + col, &lds[slot][(bt*64 + wv*8)*64]);
  };
  auto stB = [&](int slot, int kt){
    int L  = wv*8 + l8;
    int q  = c8d ^ (l8 & 7);
    int r  = (q >> 2)*64 + L;
    int col = kt + (q & 3)*8;
    gl_lds16(Bb + (size_t)r*512 + col, &lds[slot][16384 + (wv*8)*64]);
  };
  auto ldA = [&](int slot, int h){
    #pragma unroll
    for (int mi=0;mi<4;++mi){
      int R = wm*128 + (h*4+mi)*16 + fr;
      int L = R & 255, half = R >> 8;
      int c8 = (half*4 + fg) ^ (L & 7);
      afr[mi] = *(const s16x8*)&lds[slot][L*64 + c8*8];
    }
  };
  auto ldB = [&](int slot){
    #pragma unroll
    for (int nj=0;nj<4;++nj){
      int R = wn*64 + nj*16 + fr;
      int L = R & 63, half = R >> 6;
      int c8 = (half*4 + fg) ^ (L & 7);
      bfr[nj] = *(const s16x8*)&lds[slot][16384 + L*64 + c8*8];
    }
  };
  auto mm16 = [&](int h){
    #pragma unroll
    for (int mi=0;mi<4;++mi)
      #pragma unroll
      for (int nj=0;nj<4;++nj)
        acc[h*4+mi][nj] = __builtin_amdgcn_mfma_f32_16x16x32_bf16(
            afr[mi], bfr[nj], acc[h*4+mi][nj], 0,0,0);
  };

  // prologue: tile 0 only (2-slot ring)
  stA(0,0,0); stA(0,0,1); stB(0,0); stA(0,0,2); stA(0,0,3);
  asm volatile("s_waitcnt vmcnt(0)" ::: "memory");
  SBAR; SCHED;

  #pragma unroll
  for (int kt=0; kt<16; ++kt){
    int slot = kt & 1, ns = slot ^ 1, kn = (kt+1)*32;
    ldA(slot,0); ldB(slot);
    if (kt<15){
      stA(ns,kn,0); stA(ns,kn,1); stB(ns,kn); stA(ns,kn,2); stA(ns,kn,3);
    }
    PRIO1; mm16(0); PRIO0;
    ldA(slot,1);
    PRIO1; mm16(1); PRIO0;
    if (kt<15) asm volatile("s_waitcnt vmcnt(0)" ::: "memory");
    SBAR; SCHED;
  }

  // ---- fused LN2: stats over all 512 rows per n-col, then write d_out ----
  __syncthreads();
  float* red1 = (float*)&lds[0][0];
  float* red2 = red1 + 512;
  float* ms   = red2 + 512;
  float* rs   = ms + 128;
  float s1[4], s2[4];
  #pragma unroll
  for (int nj=0;nj<4;++nj){
    float a = 0.f, b2 = 0.f;
    #pragma unroll
    for (int mi=0;mi<8;++mi)
      #pragma unroll
      for (int r=0;r<4;++r){ float v = acc[mi][nj][r]; a += v; b2 += v*v; }
    s1[nj] = a; s2[nj] = b2;
  }
  #pragma unroll
  for (int off=16; off<64; off<<=1)
    #pragma unroll
    for (int nj=0;nj<4;++nj){
      s1[nj] += __shfl_xor(s1[nj], off, 64);
      s2[nj] += __shfl_xor(s2[nj], off, 64);
    }
  if (fg == 0){
    #pragma unroll
    for (int nj=0;nj<4;++nj){
      int c = wn*64 + nj*16 + fr;
      red1[wm*128 + c] = s1[nj];
      red2[wm*128 + c] = s2[nj];
    }
  }
  __syncthreads();
  if (t < 128){
    float a  = red1[t] + red1[128+t] + red1[256+t] + red1[384+t];
    float b2 = red2[t] + red2[128+t] + red2[256+t] + red2[384+t];
    float mn = a * (1.f/512.f);
    float var = b2 * (1.f/512.f) - mn*mn;
    ms[t] = mn; rs[t] = rsqrtf(var + 1e-5f);
  }
  __syncthreads();
  float mc[4], rc[4];
  #pragma unroll
  for (int nj=0;nj<4;++nj){
    int c = wn*64 + nj*16 + fr;
    mc[nj] = ms[c]; rc[nj] = rs[c];
  }
  float* ob = out + (size_t)z*CD*NS + n0;
  #pragma unroll
  for (int mi=0;mi<8;++mi)
    #pragma unroll
    for (int r=0;r<4;++r){
      int row = wm*128 + mi*16 + fg*4 + r;
      float gg = g2[row];
      #pragma unroll
      for (int nj=0;nj<4;++nj)
        ob[(size_t)row*NS + wn*64 + nj*16 + fr] = (acc[mi][nj][r] - mc[nj])*rc[nj]*gg;
    }
}

// ------- K4: context partials (no-max k-softmax: |k| <= ~3, exp safe) ------
__global__ __launch_bounds__(256) void ctxpart_k(const u16* __restrict__ qkv,
                                                 float* __restrict__ part,
                                                 float* __restrict__ mS){
  int chunk = blockIdx.x, bh = blockIdx.y;
  int b = bh >> 3, h = bh & 7;
  int t = threadIdx.x;
  int lane = t & 63, wv = t >> 6;
  int fr = lane & 15, fg = lane >> 4;
  __shared__ u16 KT[64*128];
  __shared__ u16 VT[64*128];
  __shared__ float invn_s[128];
  const u16* kb = qkv + ((size_t)(b*1536 + 512  + h*64))*NS;
  const u16* vb = qkv + ((size_t)(b*1536 + 1024 + h*64))*NS;
  int d = t >> 2, q = t & 3;

  float sloc = 0.f;

  f32x4 acc[4][4];
  #pragma unroll
  for (int i=0;i<4;++i)
    #pragma unroll
    for (int j=0;j<4;++j) acc[i][j] = (f32x4){0.f,0.f,0.f,0.f};

  for (int nt = 0; nt < 4; ++nt){
    int n0 = chunk*512 + nt*128;
    if (nt) __syncthreads();
    u16x8 kreg[4];
    #pragma unroll
    for (int s = 0; s < 4; ++s){
      int c0 = q*32 + s*8;
      u16x8 vv = *(const u16x8*)&vb[(size_t)d*NS + n0 + c0];
      *(u16x8*)&VT[d*128 + (c0 ^ ((d&7)<<3))] = vv;
      kreg[s] = *(const u16x8*)&kb[(size_t)d*NS + n0 + c0];
    }
    __syncthreads();
    {
      int col = t >> 1, half = t & 1;
      float ss = 0.f;
      #pragma unroll
      for (int e2 = 0; e2 < 32; ++e2){
        int e = half*32 + e2;
        float xv = bf2f(VT[e*128 + (col ^ ((e&7)<<3))]);
        ss += xv*xv;
      }
      ss += __shfl_xor(ss, 1, 64);
      if (half == 0) invn_s[col] = rsqrtf(ss);
    }
    __syncthreads();
    #pragma unroll
    for (int s = 0; s < 4; ++s){
      int c0 = q*32 + s*8;
      u16x8 kk = kreg[s];
      u16x8 ek;
      #pragma unroll
      for (int j = 0; j < 8; ++j){
        float e = __expf(bf2f(kk[j]));
        sloc += e;
        ek[j] = f2bf(e * invn_s[c0 + j]);
      }
      *(u16x8*)&KT[d*128 + (c0 ^ ((d&7)<<3))] = ek;
    }
    __syncthreads();
    int kc = wv*32 + fg*8;
    s16x8 af[4], bfr[4];
    #pragma unroll
    for (int i=0;i<4;++i){
      int ra = i*16 + fr;
      af[i]  = *(const s16x8*)&KT[ra*128 + (kc ^ ((ra&7)<<3))];
      bfr[i] = *(const s16x8*)&VT[ra*128 + (kc ^ ((ra&7)<<3))];
    }
    #pragma unroll
    for (int i=0;i<4;++i)
      #pragma unroll
      for (int j=0;j<4;++j)
        acc[i][j] = __builtin_amdgcn_mfma_f32_16x16x32_bf16(af[i], bfr[j], acc[i][j], 0,0,0);
  }

  sloc += __shfl_xor(sloc, 1, 64);
  sloc += __shfl_xor(sloc, 2, 64);
  if (q == 0){
    size_t mb = ((size_t)bh*8 + chunk)*128;
    mS[mb + d]      = 0.0f;
    mS[mb + 64 + d] = sloc;
  }

  float* buf0 = (float*)KT;
  float* buf1 = (float*)VT;
  auto dump = [&](float* bf){
    #pragma unroll
    for (int i=0;i<4;++i)
      #pragma unroll
      for (int j=0;j<4;++j)
        #pragma unroll
        for (int r=0;r<4;++r) bf[((i*4+j)*4+r)*64 + lane] = acc[i][j][r];
  };
  auto addin = [&](float* bf){
    #pragma unroll
    for (int i=0;i<4;++i)
      #pragma unroll
      for (int j=0;j<4;++j)
        #pragma unroll
        for (int r=0;r<4;++r) acc[i][j][r] += bf[((i*4+j)*4+r)*64 + lane];
  };
  __syncthreads();
  if (wv==1) dump(buf0);
  if (wv==3) dump(buf1);
  __syncthreads();
  if (wv==0) addin(buf0);
  if (wv==2) addin(buf1);
  __syncthreads();
  if (wv==2) dump(buf0);
  __syncthreads();
  if (wv==0){
    addin(buf0);
    float* pp = part + ((size_t)bh*8 + chunk)*4096;
    #pragma unroll
    for (int i=0;i<4;++i)
      #pragma unroll
      for (int j=0;j<4;++j)
        #pragma unroll
        for (int r=0;r<4;++r)
          pp[(i*16+fg*4+r)*64 + j*16+fr] = acc[i][j][r];
  }
}

// ---- K4b: merge 8 chunk partials with online-softmax scales -> ctx --------
__global__ void ctxred_k(const float* __restrict__ part, const float* __restrict__ mS,
                         float* __restrict__ ctx){
  int bh = blockIdx.x, t = threadIdx.x;
  __shared__ float fs[8][64];
  if (t < 64){
    int d = t;
    float mc[8];
    float mx = -3.0e38f;
    #pragma unroll
    for (int c=0;c<8;++c){ mc[c] = mS[((size_t)bh*8 + c)*128 + d]; mx = fmaxf(mx, mc[c]); }
    float es[8]; float denom = 0.f;
    #pragma unroll
    for (int c=0;c<8;++c){
      es[c] = __expf(mc[c] - mx);
      denom += es[c] * mS[((size_t)bh*8 + c)*128 + 64 + d];
    }
    float inv = 1.0f / (denom * 4096.0f);
    #pragma unroll
    for (int c=0;c<8;++c) fs[c][d] = es[c] * inv;
  }
  __syncthreads();
  #pragma unroll
  for (int i=0;i<16;++i){
    int idx = t + i*256;
    int d = idx >> 6;
    float s = 0.f;
    #pragma unroll
    for (int ch=0; ch<8; ++ch) s += fs[ch][d] * part[((size_t)bh*8 + ch)*4096 + idx];
    ctx[(size_t)bh*4096 + idx] = s;
  }
}

// ------- K5: out = softmax_feat(q)*scale @ ctx  via MFMA, GELU, gT[b][n][c] -
__global__ __launch_bounds__(256) void attnout_k(const u16* __restrict__ qkv,
                                                 const float* __restrict__ ctx,
                                                 u16* __restrict__ gT){
  int bh = blockIdx.y;
  int b = bh >> 3, h = bh & 7;
  int n0 = blockIdx.x * 256;
  int t = threadIdx.x;
  int lane = t & 63, wv = t >> 6;
  int fr = lane & 15, fg = lane >> 4;
  __shared__ u16 P[256][72];
  __shared__ u16 cT[64][72];

  const float* cs = ctx + (size_t)bh*4096;
  #pragma unroll
  for (int i=0;i<16;++i){
    int idx = i*256 + t;
    int d = idx >> 6, e = idx & 63;
    cT[e][d] = f2bf(cs[idx]);
  }

  const u16* qb = qkv + ((size_t)(b*1536 + h*64))*NS + n0 + t;
  float p[64];
  #pragma unroll
  for (int d=0; d<64; ++d) p[d] = bf2f(qb[(size_t)d*NS]);
  float m = p[0];
  #pragma unroll
  for (int d=1; d<64; ++d) m = fmaxf(m, p[d]);
  float s = 0.f;
  #pragma unroll
  for (int d=0; d<64; ++d){ p[d] = __expf(p[d]-m); s += p[d]; }
  float inv = 0.125f / s;
  #pragma unroll
  for (int d0=0; d0<8; ++d0){
    u16x8 pk;
    #pragma unroll
    for (int j=0;j<8;++j) pk[j] = f2bf(p[d0*8+j] * inv);
    *(u16x8*)&P[t][d0*8] = pk;
  }
  __syncthreads();

  f32x4 acc[4][4];
  #pragma unroll
  for (int i=0;i<4;++i)
    #pragma unroll
    for (int j=0;j<4;++j) acc[i][j] = (f32x4){0.f,0.f,0.f,0.f};
  #pragma unroll
  for (int k=0; k<2; ++k){
    s16x8 af[4], bfr[4];
    #pragma unroll
    for (int i=0;i<4;++i){
      af[i]  = *(const s16x8*)&P[wv*64 + i*16 + fr][k*32 + fg*8];
      bfr[i] = *(const s16x8*)&cT[i*16 + fr][k*32 + fg*8];
    }
    #pragma unroll
    for (int i=0;i<4;++i)
      #pragma unroll
      for (int j=0;j<4;++j)
        acc[i][j] = __builtin_amdgcn_mfma_f32_16x16x32_bf16(af[i], bfr[j], acc[i][j], 0,0,0);
  }

  #pragma unroll
  for (int i=0;i<4;++i)
    #pragma unroll
    for (int j=0;j<4;++j)
      #pragma unroll
      for (int r=0;r<4;++r)
        P[wv*64 + i*16 + fg*4 + r][j*16 + fr] = f2bf(gelu_f(acc[i][j][r]));

  int sub = lane >> 4, e4 = (lane & 15) * 4;
  #pragma unroll
  for (int it=0; it<16; ++it){
    int row = wv*64 + it*4 + sub;
    *(u16x4*)&gT[((size_t)b*NS + n0 + row)*CD + h*64 + e4] = *(u16x4*)&P[row][e4];
  }
}

extern "C" void kernel_launch(void* const* d_in, const int* in_sizes, int n_in,
                              void* d_out, int out_size, void* d_ws, size_t ws_size,
                              hipStream_t stream) {
  const float* fmap = (const float*)d_in[0];
  const float* g1   = (const float*)d_in[1];
  const float* wqkv = (const float*)d_in[2];
  const float* wout = (const float*)d_in[3];
  const float* g2   = (const float*)d_in[4];
  float* out = (float*)d_out;

  char* ws = (char*)d_ws;
  size_t off = 0;
  auto alloc = [&](size_t bytes) -> void* {
    void* p = ws + off;
    off += (bytes + 255) & ~(size_t)255;
    return p;
  };
  u16*   qkv  = (u16*)alloc((size_t)16*1536*4096*2);
  u16*   xlnT = (u16*)alloc((size_t)16*4096*512*2);    // reused as gT
  u16*   gT   = xlnT;
  float* part = (float*)alloc((size_t)128*8*4096*4);
  float* mS   = (float*)alloc((size_t)128*8*128*4);
  float* ctx  = (float*)alloc((size_t)128*4096*4);
  u16*   w1b  = (u16*)alloc((size_t)1536*512*2);
  u16*   w2b  = (u16*)alloc((size_t)512*512*2);
  if (off > ws_size) return;

  prep_w_k<<<4096, 256, 0, stream>>>(wqkv, g1, wout, w1b, w2b);
  ln1t_k<<<dim3(128,16), 512, 0, stream>>>(fmap, xlnT);
  gemm1_k<<<1536, 512, 0, stream>>>(w1b, xlnT, qkv);
  ctxpart_k<<<dim3(8,128), 256, 0, stream>>>(qkv, part, mS);
  ctxred_k<<<128, 256, 0, stream>>>(part, mS, ctx);
  attnout_k<<<dim3(16,128), 256, 0, stream>>>(qkv, ctx, gT);
  gemm2ln_k<<<dim3(32,16), 512, 0, stream>>>(w2b, gT, g2, out);
}

// Round 17
// 308.916 us; speedup vs baseline: 1.0684x; 1.0178x over previous
//
#include <hip/hip_runtime.h>

typedef unsigned short u16;
typedef __attribute__((ext_vector_type(2))) float f32x2;
typedef __attribute__((ext_vector_type(4))) float f32x4;
typedef __attribute__((ext_vector_type(8))) short s16x8;
typedef __attribute__((ext_vector_type(8))) u16 u16x8;
typedef __attribute__((ext_vector_type(4))) u16 u16x4;

#define NB 16
#define CD 512
#define NS 4096
#define NHD 8

#define SBAR  __builtin_amdgcn_s_barrier()
#define SCHED __builtin_amdgcn_sched_barrier(0)
#define PRIO1 __builtin_amdgcn_s_setprio(1)
#define PRIO0 __builtin_amdgcn_s_setprio(0)

__device__ __forceinline__ float bf2f(u16 u){
  union { unsigned int i; float f; } z; z.i = ((unsigned int)u) << 16; return z.f;
}
__device__ __forceinline__ u16 f2bf(float f){
  union { float f; unsigned int i; } z; z.f = f;
  unsigned int i = z.i;
  return (u16)((i + 0x7fffu + ((i >> 16) & 1u)) >> 16);
}
__device__ __forceinline__ float gelu_f(float x){
  return 0.5f * x * (1.0f + erff(x * 0.70710678118654752440f));
}
__device__ __forceinline__ void gl_lds16(const u16* g, u16* l){
  __builtin_amdgcn_global_load_lds((const __attribute__((address_space(1))) void*)(g),
                                   (__attribute__((address_space(3))) void*)(l), 16, 0, 0);
}

// ---------------- K0: weights -> bf16 (g1 folded into w_qkv) ----------------
__global__ void prep_w_k(const float* __restrict__ wqkv, const float* __restrict__ g1,
                         const float* __restrict__ wout, u16* __restrict__ w1b,
                         u16* __restrict__ w2b){
  int i = blockIdx.x * 256 + threadIdx.x;
  if (i < 1536*512) {
    w1b[i] = f2bf(wqkv[i] * g1[i & 511]);
  } else {
    int j = i - 1536*512;
    w2b[j] = f2bf(wout[j]);
  }
}

// ------- K1: ChanLN over c, single global read, bf16 LDS staging -----------
__global__ __launch_bounds__(512) void ln1t_k(const float* __restrict__ fmap,
                                              u16* __restrict__ xlnT){
  int b = blockIdx.y, n0 = blockIdx.x * 32;
  int t = threadIdx.x;
  int lane = t & 63, wv = t >> 6;
  __shared__ u16 Lb[512][40];
  __shared__ u16 Tt[64][36];
  __shared__ float red1[8][8][4], red2[8][8][4];
  __shared__ float mean_s[32], rstd_s[32];

  int ng = t & 7;
  float s1[4] = {0,0,0,0}, s2[4] = {0,0,0,0};
  const float* fb = fmap + ((size_t)b*CD)*NS + n0 + ng*4;
  #pragma unroll
  for (int it = 0; it < 8; ++it){
    int q = it*512 + t;
    int c = q >> 3;
    f32x4 v = *(const f32x4*)&fb[(size_t)c*NS];
    u16x4 pk;
    #pragma unroll
    for (int j = 0; j < 4; ++j){
      pk[j] = f2bf(v[j]);
      s1[j] += v[j]; s2[j] += v[j]*v[j];
    }
    *(u16x4*)&Lb[c][ng*4] = pk;
  }
  #pragma unroll
  for (int off = 8; off < 64; off <<= 1)
    #pragma unroll
    for (int j = 0; j < 4; ++j){
      s1[j] += __shfl_xor(s1[j], off, 64);
      s2[j] += __shfl_xor(s2[j], off, 64);
    }
  if (lane < 8){
    #pragma unroll
    for (int j = 0; j < 4; ++j){ red1[wv][lane][j] = s1[j]; red2[wv][lane][j] = s2[j]; }
  }
  __syncthreads();
  if (t < 32){
    int g = t >> 2, j = t & 3;
    float a = 0.f, bq = 0.f;
    #pragma unroll
    for (int w = 0; w < 8; ++w){ a += red1[w][g][j]; bq += red2[w][g][j]; }
    float mn = a * (1.f/512.f);
    float var = bq * (1.f/512.f) - mn*mn;
    mean_s[t] = mn; rstd_s[t] = rsqrtf(var + 1e-5f);
  }
  __syncthreads();

  for (int ct = 0; ct < 8; ++ct){
    {
      int cl = t >> 3, n4 = (t & 7) * 4;
      u16x4 xv = *(const u16x4*)&Lb[ct*64 + cl][n4];
      u16x4 pk;
      #pragma unroll
      for (int j = 0; j < 4; ++j)
        pk[j] = f2bf((bf2f(xv[j]) - mean_s[n4+j]) * rstd_s[n4+j]);
      *(u16x4*)&Tt[cl][n4] = pk;
    }
    __syncthreads();
    {
      int nr = t >> 4, c4 = t & 15;
      u16x4 w;
      #pragma unroll
      for (int j = 0; j < 4; ++j) w[j] = Tt[c4*4 + j][nr];
      *(u16x4*)&xlnT[((size_t)b*NS + n0 + nr)*CD + ct*64 + c4*4] = w;
    }
    __syncthreads();
  }
}

// ---------- K2: 256x256 GEMM, BK=64, lean 2-phase counted-vmcnt ------------
// EXACT r12 configuration (measured 115us, 0 conflicts, best of 9 variants).
__global__ __launch_bounds__(512) void gemm1_k(const u16* __restrict__ A,
                                               const u16* __restrict__ Bm,
                                               u16* __restrict__ Cm){
  __shared__ u16 lds[2][4][8192];
  int bi = blockIdx.x;
  int xcd = bi & 7, r2 = bi >> 3;
  int gi = r2 / 6, yy = r2 - gi*6;
  int g  = gi*8 + xcd;
  int x  = g & 15, z = g >> 4;
  int o0 = yy*256, bn0 = x*256;
  int t = threadIdx.x;
  int lane = t & 63, wv = t >> 6;
  int wm = wv >> 2, wn = wv & 3;
  int fr = lane & 15, fg = lane >> 4;
  const u16* Ab = A + (size_t)o0*512;
  const u16* Bb = Bm + ((size_t)z*NS + bn0)*512;
  int li8 = lane >> 3, scn = lane & 7;

  f32x4 acc[8][4];
  #pragma unroll
  for (int i=0;i<8;++i)
    #pragma unroll
    for (int j=0;j<4;++j) acc[i][j] = (f32x4){0.f,0.f,0.f,0.f};
  s16x8 afr[4][2];
  s16x8 bfr[2][2][2];

  auto stH = [&](int slot, int half, int kt){
    #pragma unroll
    for (int it=0; it<2; ++it){
      int li = it*64 + wv*8 + li8;
      int q  = scn ^ (li & 7);
      int row;
      if (half < 2) row = ((li>>6)<<7) + half*64 + (li & 63);
      else          row = ((li>>5)<<6) + (half-2)*32 + (li & 31);
      const u16* G = (half < 2) ? Ab : Bb;
      gl_lds16(G + (size_t)row*512 + kt + q*8, &lds[slot][half][it*4096 + wv*512]);
    }
  };
  auto ldA = [&](int slot, int mq){
    #pragma unroll
    for (int mr=0;mr<4;++mr)
      #pragma unroll
      for (int ks=0;ks<2;++ks){
        int li = wm*64 + mr*16 + fr;
        int c8 = (ks*4+fg) ^ (li & 7);
        afr[mr][ks] = *(const s16x8*)&lds[slot][mq][li*64 + c8*8];
      }
  };
  auto ldB = [&](int slot, int nq){
    #pragma unroll
    for (int nr=0;nr<2;++nr)
      #pragma unroll
      for (int ks=0;ks<2;++ks){
        int li = wn*32 + nr*16 + fr;
        int c8 = (ks*4+fg) ^ (li & 7);
        bfr[nq][nr][ks] = *(const s16x8*)&lds[slot][2+nq][li*64 + c8*8];
      }
  };
  auto mm = [&](int mq, int nq){
    #pragma unroll
    for (int mr=0;mr<4;++mr)
      #pragma unroll
      for (int nr=0;nr<2;++nr)
        #pragma unroll
        for (int ks=0;ks<2;++ks)
          acc[mq*4+mr][nq*2+nr] = __builtin_amdgcn_mfma_f32_16x16x32_bf16(
              afr[mr][ks], bfr[nq][nr][ks], acc[mq*4+mr][nq*2+nr], 0,0,0);
  };

  stH(0,0,0); stH(0,2,0); stH(0,3,0); stH(0,1,0);
  asm volatile("s_waitcnt vmcnt(2)" ::: "memory");
  SBAR; SCHED;

  #pragma unroll
  for (int kt=0; kt<8; ++kt){
    int slot = kt & 1, ns = slot ^ 1, kn = (kt+1)*64;
    bool F = kt < 7;
    ldA(slot,0); ldB(slot,0); ldB(slot,1);
    if (F){ stH(ns,0,kn); stH(ns,2,kn); stH(ns,3,kn); }
    PRIO1; mm(0,0); mm(0,1); PRIO0;
    if (F) asm volatile("s_waitcnt vmcnt(6)" ::: "memory");
    else   asm volatile("s_waitcnt vmcnt(0)" ::: "memory");
    SBAR; SCHED;
    ldA(slot,1);
    if (F) stH(ns,1,kn);
    PRIO1; mm(1,1); mm(1,0); PRIO0;
    if (F) asm volatile("s_waitcnt vmcnt(2)" ::: "memory");
    SBAR; SCHED;
  }

  size_t cb = (size_t)z * 1536 * NS;
  #pragma unroll
  for (int mq=0;mq<2;++mq)
    #pragma unroll
    for (int mr=0;mr<4;++mr)
      #pragma unroll
      for (int nq=0;nq<2;++nq)
        #pragma unroll
        for (int nr=0;nr<2;++nr){
          int row = o0 + wm*128 + mq*64 + mr*16 + fg*4;
          int col = bn0 + wn*64 + nq*32 + nr*16 + fr;
          #pragma unroll
          for (int r=0;r<4;++r)
            Cm[cb + (size_t)(row+r)*NS + col] = f2bf(acc[mq*4+mr][nq*2+nr][r]);
        }
}

// --- K6: FUSED attn-out + GEMM2 + final ChanLN -> d_out --------------------
// Per head h: cT=bf16(ctx[h]) + softmax(q)->P (unnormalized, invP kept fp32)
// -> P@cT MFMA -> gelu*inv -> Bh[2] tiles in ldB layout -> 2 k-tiles vs the
// streamed A ring. Eliminates gT write+read (134 MB) and the attnout kernel.
__global__ __launch_bounds__(512) void gemm2f_k(const u16* __restrict__ A,
                                                const u16* __restrict__ qkv,
                                                const float* __restrict__ ctx,
                                                const float* __restrict__ g2,
                                                float* __restrict__ out){
  __shared__ u16 Ar[2][16384];   // A ring: [slot][512x32 packed 256 lines x 64]
  __shared__ u16 Bh[2][4096];    // per-head B k-tiles [kt2][64 lines x 64]
  __shared__ u16 P[128][72];
  __shared__ u16 cT[64][72];
  __shared__ float invP[128];
  int x = blockIdx.x, z = blockIdx.y;
  int n0 = x*128;
  int t = threadIdx.x;
  int lane = t & 63, wv = t >> 6;
  int wm = wv >> 1, wn = wv & 1;        // GEMM wave map (4M x 2N)
  int wn2 = wv >> 2, we = wv & 3;       // attn wave map (2N x 4E)
  int fr = lane & 15, fg = lane >> 4;
  int l8 = lane >> 3, c8d = lane & 7;
  const u16* Ab = A;

  f32x4 acc[8][4];
  #pragma unroll
  for (int i=0;i<8;++i)
    #pragma unroll
    for (int j=0;j<4;++j) acc[i][j] = (f32x4){0.f,0.f,0.f,0.f};
  s16x8 afr[4], bfr[4];

  auto stA4 = [&](int slot, int kt){
    #pragma unroll
    for (int bt=0; bt<4; ++bt){
      int L  = bt*64 + wv*8 + l8;
      int q  = c8d ^ (l8 & 7);
      int r  = (q >> 2)*256 + L;
      int col = kt + (q & 3)*8;
      gl_lds16(Ab + (size_t)r*512 + col, &Ar[slot][(bt*64 + wv*8)*64]);
    }
  };
  auto ldA = [&](int slot, int h2){
    #pragma unroll
    for (int mi=0;mi<4;++mi){
      int R = wm*128 + (h2*4+mi)*16 + fr;
      int L = R & 255, half = R >> 8;
      int c8 = (half*4 + fg) ^ (L & 7);
      afr[mi] = *(const s16x8*)&Ar[slot][L*64 + c8*8];
    }
  };
  auto ldBh = [&](int kt2){
    #pragma unroll
    for (int nj=0;nj<4;++nj){
      int R = wn*64 + nj*16 + fr;
      int L = R & 63, half = R >> 6;
      int c8 = (half*4 + fg) ^ (L & 7);
      bfr[nj] = *(const s16x8*)&Bh[kt2][L*64 + c8*8];
    }
  };
  auto mm16 = [&](int h2){
    #pragma unroll
    for (int mi=0;mi<4;++mi)
      #pragma unroll
      for (int nj=0;nj<4;++nj)
        acc[h2*4+mi][nj] = __builtin_amdgcn_mfma_f32_16x16x32_bf16(
            afr[mi], bfr[nj], acc[h2*4+mi][nj], 0,0,0);
  };

  stA4(0, 0);    // s0 <- A[kt0]

  for (int h = 0; h < 8; ++h){
    // cT (bf16 transposed ctx[h])
    const float* cs = ctx + ((size_t)(z*8 + h))*4096;
    #pragma unroll
    for (int i=0;i<8;++i){
      int idx = i*512 + t;
      cT[idx & 63][idx >> 6] = f2bf(cs[idx]);
    }
    // softmax over d for this head's 128 n's: 4 threads per n (16 d each)
    {
      int nl = wv*16 + (lane & 15);
      int dg = lane >> 4;
      const u16* qb = qkv + ((size_t)(z*1536 + h*64 + dg*16))*NS + n0 + nl;
      float p[16];
      float m = -3.0e38f;
      #pragma unroll
      for (int j=0;j<16;++j){ p[j] = bf2f(qb[(size_t)j*NS]); m = fmaxf(m, p[j]); }
      m = fmaxf(m, __shfl_xor(m, 16, 64));
      m = fmaxf(m, __shfl_xor(m, 32, 64));
      float s = 0.f;
      #pragma unroll
      for (int j=0;j<16;++j){ p[j] = __expf(p[j]-m); s += p[j]; }
      s += __shfl_xor(s, 16, 64);
      s += __shfl_xor(s, 32, 64);
      u16x8 pk;
      #pragma unroll
      for (int j=0;j<8;++j) pk[j] = f2bf(p[j]);
      *(u16x8*)&P[nl][dg*16] = pk;
      #pragma unroll
      for (int j=0;j<8;++j) pk[j] = f2bf(p[8+j]);
      *(u16x8*)&P[nl][dg*16+8] = pk;
      if (dg == 0) invP[nl] = 0.125f / s;
    }
    __syncthreads();                       // P,cT ready; prev s1 reads done
    stA4(1, (2*h+1)*32);                   // s1 <- A[2h+1]

    // attn MFMA: att[128 n][64 e], wave (wn2,we) -> 4 n-frags x 1 e-frag
    f32x4 a2[4];
    #pragma unroll
    for (int i=0;i<4;++i) a2[i] = (f32x4){0.f,0.f,0.f,0.f};
    #pragma unroll
    for (int ks=0; ks<2; ++ks){
      s16x8 bfx = *(const s16x8*)&cT[we*16 + fr][ks*32 + fg*8];
      #pragma unroll
      for (int nf=0; nf<4; ++nf){
        s16x8 afx = *(const s16x8*)&P[wn2*64 + nf*16 + fr][ks*32 + fg*8];
        a2[nf] = __builtin_amdgcn_mfma_f32_16x16x32_bf16(afx, bfx, a2[nf], 0,0,0);
      }
    }
    // gelu(x*inv) -> Bh (ldB-consumable layout)
    {
      int kt2w = we >> 1;
      #pragma unroll
      for (int nf=0; nf<4; ++nf)
        #pragma unroll
        for (int r=0; r<4; ++r){
          int nl2 = wn2*64 + nf*16 + fg*4 + r;
          int e = we*16 + fr;
          int col = e & 31;
          int L = nl2 & 63;
          int c8 = ((nl2>>6)*4 + (col>>3)) ^ (L & 7);
          Bh[kt2w][L*64 + c8*8 + (col&7)] = f2bf(gelu_f(a2[nf][r] * invP[nl2]));
        }
    }
    asm volatile("s_waitcnt vmcnt(4)" ::: "memory");   // s0 (A[2h]) landed
    __syncthreads();                                   // Bh visible
    // k-tile 2h (s0)
    ldA(0,0); ldBh(0);
    PRIO1; mm16(0); PRIO0;
    ldA(0,1);
    PRIO1; mm16(1); PRIO0;
    asm volatile("s_waitcnt vmcnt(0)" ::: "memory");   // s1 (A[2h+1]) landed
    __syncthreads();                                   // all done reading s0
    if (h < 7) stA4(0, (2*h+2)*32);                    // s0 <- A[2h+2]
    // k-tile 2h+1 (s1)
    ldA(1,0); ldBh(1);
    PRIO1; mm16(0); PRIO0;
    ldA(1,1);
    PRIO1; mm16(1); PRIO0;
    // next head's first __syncthreads protects s1/P/cT reuse
  }

  __syncthreads();
  // ---- fused LN2 ----
  float* red1 = (float*)&Ar[0][0];
  float* red2 = red1 + 512;
  float* ms   = red2 + 512;
  float* rs   = ms + 128;
  float s1[4], s2[4];
  #pragma unroll
  for (int nj=0;nj<4;++nj){
    float a = 0.f, b2 = 0.f;
    #pragma unroll
    for (int mi=0;mi<8;++mi)
      #pragma unroll
      for (int r=0;r<4;++r){ float v = acc[mi][nj][r]; a += v; b2 += v*v; }
    s1[nj] = a; s2[nj] = b2;
  }
  #pragma unroll
  for (int off=16; off<64; off<<=1)
    #pragma unroll
    for (int nj=0;nj<4;++nj){
      s1[nj] += __shfl_xor(s1[nj], off, 64);
      s2[nj] += __shfl_xor(s2[nj], off, 64);
    }
  if (fg == 0){
    #pragma unroll
    for (int nj=0;nj<4;++nj){
      int c = wn*64 + nj*16 + fr;
      red1[wm*128 + c] = s1[nj];
      red2[wm*128 + c] = s2[nj];
    }
  }
  __syncthreads();
  if (t < 128){
    float a  = red1[t] + red1[128+t] + red1[256+t] + red1[384+t];
    float b2 = red2[t] + red2[128+t] + red2[256+t] + red2[384+t];
    float mn = a * (1.f/512.f);
    float var = b2 * (1.f/512.f) - mn*mn;
    ms[t] = mn; rs[t] = rsqrtf(var + 1e-5f);
  }
  __syncthreads();
  float mc[4], rc[4];
  #pragma unroll
  for (int nj=0;nj<4;++nj){
    int c = wn*64 + nj*16 + fr;
    mc[nj] = ms[c]; rc[nj] = rs[c];
  }
  float* ob = out + (size_t)z*CD*NS + n0;
  #pragma unroll
  for (int mi=0;mi<8;++mi)
    #pragma unroll
    for (int r=0;r<4;++r){
      int row = wm*128 + mi*16 + fg*4 + r;
      float gg = g2[row];
      #pragma unroll
      for (int nj=0;nj<4;++nj)
        ob[(size_t)row*NS + wn*64 + nj*16 + fr] = (acc[mi][nj][r] - mc[nj])*rc[nj]*gg;
    }
}

// ------- K4: context partials (no-max k-softmax: |k| <= ~3, exp safe) ------
__global__ __launch_bounds__(256) void ctxpart_k(const u16* __restrict__ qkv,
                                                 float* __restrict__ part,
                                                 float* __restrict__ mS){
  int chunk = blockIdx.x, bh = blockIdx.y;
  int b = bh >> 3, h = bh & 7;
  int t = threadIdx.x;
  int lane = t & 63, wv = t >> 6;
  int fr = lane & 15, fg = lane >> 4;
  __shared__ u16 KT[64*128];
  __shared__ u16 VT[64*128];
  __shared__ float invn_s[128];
  const u16* kb = qkv + ((size_t)(b*1536 + 512  + h*64))*NS;
  const u16* vb = qkv + ((size_t)(b*1536 + 1024 + h*64))*NS;
  int d = t >> 2, q = t & 3;

  float sloc = 0.f;

  f32x4 acc[4][4];
  #pragma unroll
  for (int i=0;i<4;++i)
    #pragma unroll
    for (int j=0;j<4;++j) acc[i][j] = (f32x4){0.f,0.f,0.f,0.f};

  for (int nt = 0; nt < 4; ++nt){
    int n0 = chunk*512 + nt*128;
    if (nt) __syncthreads();
    u16x8 kreg[4];
    #pragma unroll
    for (int s = 0; s < 4; ++s){
      int c0 = q*32 + s*8;
      u16x8 vv = *(const u16x8*)&vb[(size_t)d*NS + n0 + c0];
      *(u16x8*)&VT[d*128 + (c0 ^ ((d&7)<<3))] = vv;
      kreg[s] = *(const u16x8*)&kb[(size_t)d*NS + n0 + c0];
    }
    __syncthreads();
    {
      int col = t >> 1, half = t & 1;
      float ss = 0.f;
      #pragma unroll
      for (int e2 = 0; e2 < 32; ++e2){
        int e = half*32 + e2;
        float xv = bf2f(VT[e*128 + (col ^ ((e&7)<<3))]);
        ss += xv*xv;
      }
      ss += __shfl_xor(ss, 1, 64);
      if (half == 0) invn_s[col] = rsqrtf(ss);
    }
    __syncthreads();
    #pragma unroll
    for (int s = 0; s < 4; ++s){
      int c0 = q*32 + s*8;
      u16x8 kk = kreg[s];
      u16x8 ek;
      #pragma unroll
      for (int j = 0; j < 8; ++j){
        float e = __expf(bf2f(kk[j]));
        sloc += e;
        ek[j] = f2bf(e * invn_s[c0 + j]);
      }
      *(u16x8*)&KT[d*128 + (c0 ^ ((d&7)<<3))] = ek;
    }
    __syncthreads();
    int kc = wv*32 + fg*8;
    s16x8 af[4], bfr[4];
    #pragma unroll
    for (int i=0;i<4;++i){
      int ra = i*16 + fr;
      af[i]  = *(const s16x8*)&KT[ra*128 + (kc ^ ((ra&7)<<3))];
      bfr[i] = *(const s16x8*)&VT[ra*128 + (kc ^ ((ra&7)<<3))];
    }
    #pragma unroll
    for (int i=0;i<4;++i)
      #pragma unroll
      for (int j=0;j<4;++j)
        acc[i][j] = __builtin_amdgcn_mfma_f32_16x16x32_bf16(af[i], bfr[j], acc[i][j], 0,0,0);
  }

  sloc += __shfl_xor(sloc, 1, 64);
  sloc += __shfl_xor(sloc, 2, 64);
  if (q == 0){
    size_t mb = ((size_t)bh*8 + chunk)*128;
    mS[mb + d]      = 0.0f;
    mS[mb + 64 + d] = sloc;
  }

  float* buf0 = (float*)KT;
  float* buf1 = (float*)VT;
  auto dump = [&](float* bf){
    #pragma unroll
    for (int i=0;i<4;++i)
      #pragma unroll
      for (int j=0;j<4;++j)
        #pragma unroll
        for (int r=0;r<4;++r) bf[((i*4+j)*4+r)*64 + lane] = acc[i][j][r];
  };
  auto addin = [&](float* bf){
    #pragma unroll
    for (int i=0;i<4;++i)
      #pragma unroll
      for (int j=0;j<4;++j)
        #pragma unroll
        for (int r=0;r<4;++r) acc[i][j][r] += bf[((i*4+j)*4+r)*64 + lane];
  };
  __syncthreads();
  if (wv==1) dump(buf0);
  if (wv==3) dump(buf1);
  __syncthreads();
  if (wv==0) addin(buf0);
  if (wv==2) addin(buf1);
  __syncthreads();
  if (wv==2) dump(buf0);
  __syncthreads();
  if (wv==0){
    addin(buf0);
    float* pp = part + ((size_t)bh*8 + chunk)*4096;
    #pragma unroll
    for (int i=0;i<4;++i)
      #pragma unroll
      for (int j=0;j<4;++j)
        #pragma unroll
        for (int r=0;r<4;++r)
          pp[(i*16+fg*4+r)*64 + j*16+fr] = acc[i][j][r];
  }
}

// ---- K4b: merge 8 chunk partials with online-softmax scales -> ctx --------
__global__ void ctxred_k(const float* __restrict__ part, const float* __restrict__ mS,
                         float* __restrict__ ctx){
  int bh = blockIdx.x, t = threadIdx.x;
  __shared__ float fs[8][64];
  if (t < 64){
    int d = t;
    float mc[8];
    float mx = -3.0e38f;
    #pragma unroll
    for (int c=0;c<8;++c){ mc[c] = mS[((size_t)bh*8 + c)*128 + d]; mx = fmaxf(mx, mc[c]); }
    float es[8]; float denom = 0.f;
    #pragma unroll
    for (int c=0;c<8;++c){
      es[c] = __expf(mc[c] - mx);
      denom += es[c] * mS[((size_t)bh*8 + c)*128 + 64 + d];
    }
    float inv = 1.0f / (denom * 4096.0f);
    #pragma unroll
    for (int c=0;c<8;++c) fs[c][d] = es[c] * inv;
  }
  __syncthreads();
  #pragma unroll
  for (int i=0;i<16;++i){
    int idx = t + i*256;
    int d = idx >> 6;
    float s = 0.f;
    #pragma unroll
    for (int ch=0; ch<8; ++ch) s += fs[ch][d] * part[((size_t)bh*8 + ch)*4096 + idx];
    ctx[(size_t)bh*4096 + idx] = s;
  }
}

extern "C" void kernel_launch(void* const* d_in, const int* in_sizes, int n_in,
                              void* d_out, int out_size, void* d_ws, size_t ws_size,
                              hipStream_t stream) {
  const float* fmap = (const float*)d_in[0];
  const float* g1   = (const float*)d_in[1];
  const float* wqkv = (const float*)d_in[2];
  const float* wout = (const float*)d_in[3];
  const float* g2   = (const float*)d_in[4];
  float* out = (float*)d_out;

  char* ws = (char*)d_ws;
  size_t off = 0;
  auto alloc = [&](size_t bytes) -> void* {
    void* p = ws + off;
    off += (bytes + 255) & ~(size_t)255;
    return p;
  };
  u16*   qkv  = (u16*)alloc((size_t)16*1536*4096*2);
  u16*   xlnT = (u16*)alloc((size_t)16*4096*512*2);
  float* part = (float*)alloc((size_t)128*8*4096*4);
  float* mS   = (float*)alloc((size_t)128*8*128*4);
  float* ctx  = (float*)alloc((size_t)128*4096*4);
  u16*   w1b  = (u16*)alloc((size_t)1536*512*2);
  u16*   w2b  = (u16*)alloc((size_t)512*512*2);
  if (off > ws_size) return;

  prep_w_k<<<4096, 256, 0, stream>>>(wqkv, g1, wout, w1b, w2b);
  ln1t_k<<<dim3(128,16), 512, 0, stream>>>(fmap, xlnT);
  gemm1_k<<<1536, 512, 0, stream>>>(w1b, xlnT, qkv);
  ctxpart_k<<<dim3(8,128), 256, 0, stream>>>(qkv, part, mS);
  ctxred_k<<<128, 256, 0, stream>>>(part, mS, ctx);
  gemm2f_k<<<dim3(32,16), 512, 0, stream>>>(w2b, qkv, ctx, g2, out);
}

// Round 18
// 287.500 us; speedup vs baseline: 1.1479x; 1.0745x over previous
//
#include <hip/hip_runtime.h>

typedef unsigned short u16;
typedef __attribute__((ext_vector_type(2))) float f32x2;
typedef __attribute__((ext_vector_type(4))) float f32x4;
typedef __attribute__((ext_vector_type(8))) short s16x8;
typedef __attribute__((ext_vector_type(8))) u16 u16x8;
typedef __attribute__((ext_vector_type(4))) u16 u16x4;

#define NB 16
#define CD 512
#define NS 4096
#define NHD 8

#define SBAR  __builtin_amdgcn_s_barrier()
#define SCHED __builtin_amdgcn_sched_barrier(0)
#define PRIO1 __builtin_amdgcn_s_setprio(1)
#define PRIO0 __builtin_amdgcn_s_setprio(0)

__device__ __forceinline__ float bf2f(u16 u){
  union { unsigned int i; float f; } z; z.i = ((unsigned int)u) << 16; return z.f;
}
__device__ __forceinline__ u16 f2bf(float f){
  union { float f; unsigned int i; } z; z.f = f;
  unsigned int i = z.i;
  return (u16)((i + 0x7fffu + ((i >> 16) & 1u)) >> 16);
}
__device__ __forceinline__ float gelu_f(float x){
  return 0.5f * x * (1.0f + erff(x * 0.70710678118654752440f));
}
__device__ __forceinline__ void gl_lds16(const u16* g, u16* l){
  __builtin_amdgcn_global_load_lds((const __attribute__((address_space(1))) void*)(g),
                                   (__attribute__((address_space(3))) void*)(l), 16, 0, 0);
}

// ---------------- K0: weights -> bf16 (g1 folded into w_qkv) ----------------
__global__ void prep_w_k(const float* __restrict__ wqkv, const float* __restrict__ g1,
                         const float* __restrict__ wout, u16* __restrict__ w1b,
                         u16* __restrict__ w2b){
  int i = blockIdx.x * 256 + threadIdx.x;
  if (i < 1536*512) {
    w1b[i] = f2bf(wqkv[i] * g1[i & 511]);
  } else {
    int j = i - 1536*512;
    w2b[j] = f2bf(wout[j]);
  }
}

// ------- K1: ChanLN over c, single global read, bf16 LDS staging -----------
__global__ __launch_bounds__(512) void ln1t_k(const float* __restrict__ fmap,
                                              u16* __restrict__ xlnT){
  int b = blockIdx.y, n0 = blockIdx.x * 32;
  int t = threadIdx.x;
  int lane = t & 63, wv = t >> 6;
  __shared__ u16 Lb[512][40];
  __shared__ u16 Tt[64][36];
  __shared__ float red1[8][8][4], red2[8][8][4];
  __shared__ float mean_s[32], rstd_s[32];

  int ng = t & 7;
  float s1[4] = {0,0,0,0}, s2[4] = {0,0,0,0};
  const float* fb = fmap + ((size_t)b*CD)*NS + n0 + ng*4;
  #pragma unroll
  for (int it = 0; it < 8; ++it){
    int q = it*512 + t;
    int c = q >> 3;
    f32x4 v = *(const f32x4*)&fb[(size_t)c*NS];
    u16x4 pk;
    #pragma unroll
    for (int j = 0; j < 4; ++j){
      pk[j] = f2bf(v[j]);
      s1[j] += v[j]; s2[j] += v[j]*v[j];
    }
    *(u16x4*)&Lb[c][ng*4] = pk;
  }
  #pragma unroll
  for (int off = 8; off < 64; off <<= 1)
    #pragma unroll
    for (int j = 0; j < 4; ++j){
      s1[j] += __shfl_xor(s1[j], off, 64);
      s2[j] += __shfl_xor(s2[j], off, 64);
    }
  if (lane < 8){
    #pragma unroll
    for (int j = 0; j < 4; ++j){ red1[wv][lane][j] = s1[j]; red2[wv][lane][j] = s2[j]; }
  }
  __syncthreads();
  if (t < 32){
    int g = t >> 2, j = t & 3;
    float a = 0.f, bq = 0.f;
    #pragma unroll
    for (int w = 0; w < 8; ++w){ a += red1[w][g][j]; bq += red2[w][g][j]; }
    float mn = a * (1.f/512.f);
    float var = bq * (1.f/512.f) - mn*mn;
    mean_s[t] = mn; rstd_s[t] = rsqrtf(var + 1e-5f);
  }
  __syncthreads();

  for (int ct = 0; ct < 8; ++ct){
    {
      int cl = t >> 3, n4 = (t & 7) * 4;
      u16x4 xv = *(const u16x4*)&Lb[ct*64 + cl][n4];
      u16x4 pk;
      #pragma unroll
      for (int j = 0; j < 4; ++j)
        pk[j] = f2bf((bf2f(xv[j]) - mean_s[n4+j]) * rstd_s[n4+j]);
      *(u16x4*)&Tt[cl][n4] = pk;
    }
    __syncthreads();
    {
      int nr = t >> 4, c4 = t & 15;
      u16x4 w;
      #pragma unroll
      for (int j = 0; j < 4; ++j) w[j] = Tt[c4*4 + j][nr];
      *(u16x4*)&xlnT[((size_t)b*NS + n0 + nr)*CD + ct*64 + c4*4] = w;
    }
    __syncthreads();
  }
}

// ---------- K2a: q-GEMM (512 rows), r12 loop verbatim -----------------------
__global__ __launch_bounds__(512) void gemm1q_k(const u16* __restrict__ A,
                                                const u16* __restrict__ Bm,
                                                u16* __restrict__ Q){
  __shared__ u16 lds[8][8192];   // [slot*4+half]
  int bi = blockIdx.x;
  int xcd = bi & 7, r2 = bi >> 3;   // 0..63
  int yy = r2 & 1, gi = r2 >> 1;
  int g  = gi*8 + xcd;
  int x  = g & 15, z = g >> 4;
  int o0 = yy*256, bn0 = x*256;
  int t = threadIdx.x;
  int lane = t & 63, wv = t >> 6;
  int wm = wv >> 2, wn = wv & 3;
  int fr = lane & 15, fg = lane >> 4;
  const u16* Ab = A + (size_t)o0*512;
  const u16* Bb = Bm + ((size_t)z*NS + bn0)*512;
  int li8 = lane >> 3, scn = lane & 7;

  f32x4 acc[8][4];
  #pragma unroll
  for (int i=0;i<8;++i)
    #pragma unroll
    for (int j=0;j<4;++j) acc[i][j] = (f32x4){0.f,0.f,0.f,0.f};
  s16x8 afr[4][2];
  s16x8 bfr[2][2][2];

  auto stH = [&](int slot, int half, int kt){
    #pragma unroll
    for (int it=0; it<2; ++it){
      int li = it*64 + wv*8 + li8;
      int q  = scn ^ (li & 7);
      int row;
      if (half < 2) row = ((li>>6)<<7) + half*64 + (li & 63);
      else          row = ((li>>5)<<6) + (half-2)*32 + (li & 31);
      const u16* G = (half < 2) ? Ab : Bb;
      gl_lds16(G + (size_t)row*512 + kt + q*8, &lds[slot*4+half][it*4096 + wv*512]);
    }
  };
  auto ldA = [&](int slot, int mq){
    #pragma unroll
    for (int mr=0;mr<4;++mr)
      #pragma unroll
      for (int ks=0;ks<2;++ks){
        int li = wm*64 + mr*16 + fr;
        int c8 = (ks*4+fg) ^ (li & 7);
        afr[mr][ks] = *(const s16x8*)&lds[slot*4+mq][li*64 + c8*8];
      }
  };
  auto ldB = [&](int slot, int nq){
    #pragma unroll
    for (int nr=0;nr<2;++nr)
      #pragma unroll
      for (int ks=0;ks<2;++ks){
        int li = wn*32 + nr*16 + fr;
        int c8 = (ks*4+fg) ^ (li & 7);
        bfr[nq][nr][ks] = *(const s16x8*)&lds[slot*4+2+nq][li*64 + c8*8];
      }
  };
  auto mm = [&](int mq, int nq){
    #pragma unroll
    for (int mr=0;mr<4;++mr)
      #pragma unroll
      for (int nr=0;nr<2;++nr)
        #pragma unroll
        for (int ks=0;ks<2;++ks)
          acc[mq*4+mr][nq*2+nr] = __builtin_amdgcn_mfma_f32_16x16x32_bf16(
              afr[mr][ks], bfr[nq][nr][ks], acc[mq*4+mr][nq*2+nr], 0,0,0);
  };

  stH(0,0,0); stH(0,2,0); stH(0,3,0); stH(0,1,0);
  asm volatile("s_waitcnt vmcnt(2)" ::: "memory");
  SBAR; SCHED;

  #pragma unroll
  for (int kt=0; kt<8; ++kt){
    int slot = kt & 1, ns = slot ^ 1, kn = (kt+1)*64;
    bool F = kt < 7;
    ldA(slot,0); ldB(slot,0); ldB(slot,1);
    if (F){ stH(ns,0,kn); stH(ns,2,kn); stH(ns,3,kn); }
    PRIO1; mm(0,0); mm(0,1); PRIO0;
    if (F) asm volatile("s_waitcnt vmcnt(6)" ::: "memory");
    else   asm volatile("s_waitcnt vmcnt(0)" ::: "memory");
    SBAR; SCHED;
    ldA(slot,1);
    if (F) stH(ns,1,kn);
    PRIO1; mm(1,1); mm(1,0); PRIO0;
    if (F) asm volatile("s_waitcnt vmcnt(2)" ::: "memory");
    SBAR; SCHED;
  }

  size_t cb = (size_t)z * 512 * NS;
  #pragma unroll
  for (int mq=0;mq<2;++mq)
    #pragma unroll
    for (int mr=0;mr<4;++mr)
      #pragma unroll
      for (int nq=0;nq<2;++nq)
        #pragma unroll
        for (int nr=0;nr<2;++nr){
          int row = o0 + wm*128 + mq*64 + mr*16 + fg*4;
          int col = bn0 + wn*64 + nq*32 + nr*16 + fr;
          #pragma unroll
          for (int r=0;r<4;++r)
            Q[cb + (size_t)(row+r)*NS + col] = f2bf(acc[mq*4+mr][nq*2+nr][r]);
        }
}

// ---------- K2b: kv-GEMM + FUSED ctx partial (no k/v HBM round-trip) --------
// Block (hp,x,z): A rows = k heads {2hp,2hp+1} (local 0-127) + v same heads
// (local 128-255); n-chunk = x (256 wide). After the K-loop: acc -> LDS as
// ek=exp(k) (KT tiles, bf16) and vn=v*invn (VT, norm via fg-shfl), ctxpart's
// proven [64][128] swizzled layout; then ctx MFMA (wave=(g,hh,ksl), K=64) +
// sloc readback; reduce -> part[bh*16+x], mS. k,v never touch HBM.
__global__ __launch_bounds__(512) void gemm1kv_k(const u16* __restrict__ A,
                                                 const u16* __restrict__ Bm,
                                                 float* __restrict__ part,
                                                 float* __restrict__ mS){
  __shared__ u16 lds[8][8192];   // loop ring; epilogue: t0-3=KT[g][hh], t4-7=VT
  int bi = blockIdx.x;
  int xcd = bi & 7, r2 = bi >> 3;   // 0..127
  int hp = r2 & 3, gg = r2 >> 2;
  int g8 = gg*8 + xcd;
  int x  = g8 & 15, z = g8 >> 4;
  int bn0 = x*256;
  int t = threadIdx.x;
  int lane = t & 63, wv = t >> 6;
  int wm = wv >> 2, wn = wv & 3;
  int fr = lane & 15, fg = lane >> 4;
  const u16* Akb = A + (size_t)(512  + hp*128)*512;
  const u16* Avb = A + (size_t)(1024 + hp*128)*512;
  const u16* Bb  = Bm + ((size_t)z*NS + bn0)*512;
  int li8 = lane >> 3, scn = lane & 7;

  f32x4 acc[8][4];
  #pragma unroll
  for (int i=0;i<8;++i)
    #pragma unroll
    for (int j=0;j<4;++j) acc[i][j] = (f32x4){0.f,0.f,0.f,0.f};
  s16x8 afr[4][2];
  s16x8 bfr[2][2][2];

  auto stH = [&](int slot, int half, int kt){
    #pragma unroll
    for (int it=0; it<2; ++it){
      int li = it*64 + wv*8 + li8;
      int q  = scn ^ (li & 7);
      if (half < 2){
        int rr = half*64 + (li & 63);
        const u16* G = it ? Avb : Akb;     // local rows <128 = k, >=128 = v
        gl_lds16(G + (size_t)rr*512 + kt + q*8, &lds[slot*4+half][it*4096 + wv*512]);
      } else {
        int row = ((li>>5)<<6) + (half-2)*32 + (li & 31);
        gl_lds16(Bb + (size_t)row*512 + kt + q*8, &lds[slot*4+half][it*4096 + wv*512]);
      }
    }
  };
  auto ldA = [&](int slot, int mq){
    #pragma unroll
    for (int mr=0;mr<4;++mr)
      #pragma unroll
      for (int ks=0;ks<2;++ks){
        int li = wm*64 + mr*16 + fr;
        int c8 = (ks*4+fg) ^ (li & 7);
        afr[mr][ks] = *(const s16x8*)&lds[slot*4+mq][li*64 + c8*8];
      }
  };
  auto ldB = [&](int slot, int nq){
    #pragma unroll
    for (int nr=0;nr<2;++nr)
      #pragma unroll
      for (int ks=0;ks<2;++ks){
        int li = wn*32 + nr*16 + fr;
        int c8 = (ks*4+fg) ^ (li & 7);
        bfr[nq][nr][ks] = *(const s16x8*)&lds[slot*4+2+nq][li*64 + c8*8];
      }
  };
  auto mm = [&](int mq, int nq){
    #pragma unroll
    for (int mr=0;mr<4;++mr)
      #pragma unroll
      for (int nr=0;nr<2;++nr)
        #pragma unroll
        for (int ks=0;ks<2;++ks)
          acc[mq*4+mr][nq*2+nr] = __builtin_amdgcn_mfma_f32_16x16x32_bf16(
              afr[mr][ks], bfr[nq][nr][ks], acc[mq*4+mr][nq*2+nr], 0,0,0);
  };

  stH(0,0,0); stH(0,2,0); stH(0,3,0); stH(0,1,0);
  asm volatile("s_waitcnt vmcnt(2)" ::: "memory");
  SBAR; SCHED;

  #pragma unroll
  for (int kt=0; kt<8; ++kt){
    int slot = kt & 1, ns = slot ^ 1, kn = (kt+1)*64;
    bool F = kt < 7;
    ldA(slot,0); ldB(slot,0); ldB(slot,1);
    if (F){ stH(ns,0,kn); stH(ns,2,kn); stH(ns,3,kn); }
    PRIO1; mm(0,0); mm(0,1); PRIO0;
    if (F) asm volatile("s_waitcnt vmcnt(6)" ::: "memory");
    else   asm volatile("s_waitcnt vmcnt(0)" ::: "memory");
    SBAR; SCHED;
    ldA(slot,1);
    if (F) stH(ns,1,kn);
    PRIO1; mm(1,1); mm(1,0); PRIO0;
    if (F) asm volatile("s_waitcnt vmcnt(2)" ::: "memory");
    SBAR; SCHED;
  }

  // ---- Phase 1: acc -> KT/VT tiles (ring dead; vmcnt drained at kt=7) ----
  if (wm == 0){
    #pragma unroll
    for (int mq=0;mq<2;++mq)
      #pragma unroll
      for (int mr=0;mr<4;++mr)
        #pragma unroll
        for (int nj=0;nj<4;++nj){
          int nq = nj>>1, nr = nj&1;
          #pragma unroll
          for (int r=0;r<4;++r){
            int d  = mr*16 + fg*4 + r;
            int nl = wn*64 + nq*32 + nr*16 + fr;
            int hh = nl >> 7, n1 = nl & 127;
            lds[mq*2+hh][d*128 + (n1 ^ ((d&7)<<3))] = f2bf(__expf(acc[mq*4+mr][nj][r]));
          }
        }
  } else {
    float ss[2][4];
    #pragma unroll
    for (int mq=0;mq<2;++mq)
      #pragma unroll
      for (int nj=0;nj<4;++nj){
        float s = 0.f;
        #pragma unroll
        for (int mr=0;mr<4;++mr)
          #pragma unroll
          for (int r=0;r<4;++r){ float v = acc[mq*4+mr][nj][r]; s += v*v; }
        s += __shfl_xor(s, 16, 64);
        s += __shfl_xor(s, 32, 64);
        ss[mq][nj] = rsqrtf(s);
      }
    #pragma unroll
    for (int mq=0;mq<2;++mq)
      #pragma unroll
      for (int mr=0;mr<4;++mr)
        #pragma unroll
        for (int nj=0;nj<4;++nj){
          int nq = nj>>1, nr = nj&1;
          #pragma unroll
          for (int r=0;r<4;++r){
            int e  = mr*16 + fg*4 + r;
            int nl = wn*64 + nq*32 + nr*16 + fr;
            int hh = nl >> 7, n1 = nl & 127;
            lds[4 + mq*2+hh][e*128 + (n1 ^ ((e&7)<<3))] = f2bf(acc[mq*4+mr][nj][r] * ss[mq][nj]);
          }
        }
  }
  __syncthreads();

  // ---- Phase 2: ctx MFMA (wave = (g, hh, ksl)) + sloc readback -----------
  int eg = wv >> 2, ej = wv & 3, ksl = ej & 1;
  const u16* KTt = &lds[eg*2 + (ej>>1)][0];
  const u16* VTt = &lds[4 + eg*2 + (ej>>1)][0];
  f32x4 a2[4][4];
  #pragma unroll
  for (int i=0;i<4;++i)
    #pragma unroll
    for (int j=0;j<4;++j) a2[i][j] = (f32x4){0.f,0.f,0.f,0.f};
  #pragma unroll
  for (int ks2=0; ks2<2; ++ks2){
    int kc = ksl*64 + ks2*32 + fg*8;
    s16x8 af[4], bf_[4];
    #pragma unroll
    for (int i=0;i<4;++i){
      int ra = i*16 + fr;
      af[i]  = *(const s16x8*)&KTt[ra*128 + (kc ^ ((ra&7)<<3))];
      bf_[i] = *(const s16x8*)&VTt[ra*128 + (kc ^ ((ra&7)<<3))];
    }
    #pragma unroll
    for (int i=0;i<4;++i)
      #pragma unroll
      for (int j=0;j<4;++j)
        a2[i][j] = __builtin_amdgcn_mfma_f32_16x16x32_bf16(af[i], bf_[j], a2[i][j], 0,0,0);
  }
  float slc = 0.f;
  {
    int d = lane;
    #pragma unroll
    for (int cc=0; cc<8; ++cc){
      int c0 = ksl*64 + cc*8;
      u16x8 vv = *(const u16x8*)&KTt[d*128 + (c0 ^ ((d&7)<<3))];
      #pragma unroll
      for (int jj=0;jj<8;++jj) slc += bf2f(vv[jj]);
    }
  }
  __syncthreads();

  // ---- Phase 3: dumps (tiles g*3+0..2) + slocB (tile 6) ------------------
  if (ej >= 1){
    float* dbuf = (float*)&lds[eg*3 + (ej-1)][0];
    #pragma unroll
    for (int i=0;i<4;++i)
      #pragma unroll
      for (int j=0;j<4;++j)
        #pragma unroll
        for (int r=0;r<4;++r) dbuf[((i*4+j)*4+r)*64 + lane] = a2[i][j][r];
  }
  ((float*)&lds[6][0])[eg*256 + ej*64 + lane] = slc;
  __syncthreads();

  // ---- Phase 4: reduce + write part/mS ------------------------------------
  int bh = z*8 + hp*2 + eg;
  size_t base = (size_t)bh*16 + x;
  if (ej == 0){
    #pragma unroll
    for (int bb=0; bb<3; ++bb){
      float* dbuf = (float*)&lds[eg*3 + bb][0];
      #pragma unroll
      for (int i=0;i<4;++i)
        #pragma unroll
        for (int j=0;j<4;++j)
          #pragma unroll
          for (int r=0;r<4;++r) a2[i][j][r] += dbuf[((i*4+j)*4+r)*64 + lane];
    }
    float* pp = part + base*4096;
    #pragma unroll
    for (int i=0;i<4;++i)
      #pragma unroll
      for (int j=0;j<4;++j)
        #pragma unroll
        for (int r=0;r<4;++r)
          pp[(i*16+fg*4+r)*64 + j*16+fr] = a2[i][j][r];
  } else if (ej == 1){
    float* sB = (float*)&lds[6][0];
    float s = sB[eg*256 + lane] + sB[eg*256 + 64 + lane]
            + sB[eg*256 + 128 + lane] + sB[eg*256 + 192 + lane];
    mS[base*128 + lane]      = 0.0f;
    mS[base*128 + 64 + lane] = s;
  }
}

// ---- K4b: merge 16 chunk partials -> ctx -----------------------------------
__global__ void ctxred_k(const float* __restrict__ part, const float* __restrict__ mS,
                         float* __restrict__ ctx){
  int bh = blockIdx.x, t = threadIdx.x;
  __shared__ float fs[16][64];
  if (t < 64){
    int d = t;
    float denom = 0.f;
    #pragma unroll
    for (int c=0;c<16;++c)
      denom += mS[((size_t)bh*16 + c)*128 + 64 + d];
    float inv = 1.0f / (denom * 4096.0f);
    #pragma unroll
    for (int c=0;c<16;++c) fs[c][d] = inv;
  }
  __syncthreads();
  #pragma unroll
  for (int i=0;i<16;++i){
    int idx = t + i*256;
    int d = idx >> 6;
    float s = 0.f;
    #pragma unroll
    for (int ch=0; ch<16; ++ch) s += fs[ch][d] * part[((size_t)bh*16 + ch)*4096 + idx];
    ctx[(size_t)bh*4096 + idx] = s;
  }
}

// --- K6: FUSED attn-out + GEMM2 + final ChanLN -> d_out --------------------
__global__ __launch_bounds__(512) void gemm2f_k(const u16* __restrict__ A,
                                                const u16* __restrict__ q,
                                                const float* __restrict__ ctx,
                                                const float* __restrict__ g2,
                                                float* __restrict__ out){
  __shared__ u16 Ar[2][16384];
  __shared__ u16 Bh[2][4096];
  __shared__ u16 P[128][72];
  __shared__ u16 cT[64][72];
  __shared__ float invP[128];
  int x = blockIdx.x, z = blockIdx.y;
  int n0 = x*128;
  int t = threadIdx.x;
  int lane = t & 63, wv = t >> 6;
  int wm = wv >> 1, wn = wv & 1;
  int wn2 = wv >> 2, we = wv & 3;
  int fr = lane & 15, fg = lane >> 4;
  int l8 = lane >> 3, c8d = lane & 7;
  const u16* Ab = A;

  f32x4 acc[8][4];
  #pragma unroll
  for (int i=0;i<8;++i)
    #pragma unroll
    for (int j=0;j<4;++j) acc[i][j] = (f32x4){0.f,0.f,0.f,0.f};
  s16x8 afr[4], bfr[4];

  auto stA4 = [&](int slot, int kt){
    #pragma unroll
    for (int bt=0; bt<4; ++bt){
      int L  = bt*64 + wv*8 + l8;
      int qq = c8d ^ (l8 & 7);
      int r  = (qq >> 2)*256 + L;
      int col = kt + (qq & 3)*8;
      gl_lds16(Ab + (size_t)r*512 + col, &Ar[slot][(bt*64 + wv*8)*64]);
    }
  };
  auto ldA = [&](int slot, int h2){
    #pragma unroll
    for (int mi=0;mi<4;++mi){
      int R = wm*128 + (h2*4+mi)*16 + fr;
      int L = R & 255, half = R >> 8;
      int c8 = (half*4 + fg) ^ (L & 7);
      afr[mi] = *(const s16x8*)&Ar[slot][L*64 + c8*8];
    }
  };
  auto ldBh = [&](int kt2){
    #pragma unroll
    for (int nj=0;nj<4;++nj){
      int R = wn*64 + nj*16 + fr;
      int L = R & 63, half = R >> 6;
      int c8 = (half*4 + fg) ^ (L & 7);
      bfr[nj] = *(const s16x8*)&Bh[kt2][L*64 + c8*8];
    }
  };
  auto mm16 = [&](int h2){
    #pragma unroll
    for (int mi=0;mi<4;++mi)
      #pragma unroll
      for (int nj=0;nj<4;++nj)
        acc[h2*4+mi][nj] = __builtin_amdgcn_mfma_f32_16x16x32_bf16(
            afr[mi], bfr[nj], acc[h2*4+mi][nj], 0,0,0);
  };

  stA4(0, 0);

  for (int h = 0; h < 8; ++h){
    const float* cs = ctx + ((size_t)(z*8 + h))*4096;
    #pragma unroll
    for (int i=0;i<8;++i){
      int idx = i*512 + t;
      cT[idx & 63][idx >> 6] = f2bf(cs[idx]);
    }
    {
      int nl = wv*16 + (lane & 15);
      int dg = lane >> 4;
      const u16* qb = q + ((size_t)(z*512 + h*64 + dg*16))*NS + n0 + nl;
      float p[16];
      float m = -3.0e38f;
      #pragma unroll
      for (int j=0;j<16;++j){ p[j] = bf2f(qb[(size_t)j*NS]); m = fmaxf(m, p[j]); }
      m = fmaxf(m, __shfl_xor(m, 16, 64));
      m = fmaxf(m, __shfl_xor(m, 32, 64));
      float s = 0.f;
      #pragma unroll
      for (int j=0;j<16;++j){ p[j] = __expf(p[j]-m); s += p[j]; }
      s += __shfl_xor(s, 16, 64);
      s += __shfl_xor(s, 32, 64);
      u16x8 pk;
      #pragma unroll
      for (int j=0;j<8;++j) pk[j] = f2bf(p[j]);
      *(u16x8*)&P[nl][dg*16] = pk;
      #pragma unroll
      for (int j=0;j<8;++j) pk[j] = f2bf(p[8+j]);
      *(u16x8*)&P[nl][dg*16+8] = pk;
      if (dg == 0) invP[nl] = 0.125f / s;
    }
    __syncthreads();
    stA4(1, (2*h+1)*32);

    f32x4 a2[4];
    #pragma unroll
    for (int i=0;i<4;++i) a2[i] = (f32x4){0.f,0.f,0.f,0.f};
    #pragma unroll
    for (int ks=0; ks<2; ++ks){
      s16x8 bfx = *(const s16x8*)&cT[we*16 + fr][ks*32 + fg*8];
      #pragma unroll
      for (int nf=0; nf<4; ++nf){
        s16x8 afx = *(const s16x8*)&P[wn2*64 + nf*16 + fr][ks*32 + fg*8];
        a2[nf] = __builtin_amdgcn_mfma_f32_16x16x32_bf16(afx, bfx, a2[nf], 0,0,0);
      }
    }
    {
      int kt2w = we >> 1;
      #pragma unroll
      for (int nf=0; nf<4; ++nf)
        #pragma unroll
        for (int r=0; r<4; ++r){
          int nl2 = wn2*64 + nf*16 + fg*4 + r;
          int e = we*16 + fr;
          int col = e & 31;
          int L = nl2 & 63;
          int c8 = ((nl2>>6)*4 + (col>>3)) ^ (L & 7);
          Bh[kt2w][L*64 + c8*8 + (col&7)] = f2bf(gelu_f(a2[nf][r] * invP[nl2]));
        }
    }
    asm volatile("s_waitcnt vmcnt(4)" ::: "memory");
    __syncthreads();
    ldA(0,0); ldBh(0);
    PRIO1; mm16(0); PRIO0;
    ldA(0,1);
    PRIO1; mm16(1); PRIO0;
    asm volatile("s_waitcnt vmcnt(0)" ::: "memory");
    __syncthreads();
    if (h < 7) stA4(0, (2*h+2)*32);
    ldA(1,0); ldBh(1);
    PRIO1; mm16(0); PRIO0;
    ldA(1,1);
    PRIO1; mm16(1); PRIO0;
  }

  __syncthreads();
  float* red1 = (float*)&Ar[0][0];
  float* red2 = red1 + 512;
  float* ms   = red2 + 512;
  float* rs   = ms + 128;
  float s1[4], s2[4];
  #pragma unroll
  for (int nj=0;nj<4;++nj){
    float a = 0.f, b2 = 0.f;
    #pragma unroll
    for (int mi=0;mi<8;++mi)
      #pragma unroll
      for (int r=0;r<4;++r){ float v = acc[mi][nj][r]; a += v; b2 += v*v; }
    s1[nj] = a; s2[nj] = b2;
  }
  #pragma unroll
  for (int off=16; off<64; off<<=1)
    #pragma unroll
    for (int nj=0;nj<4;++nj){
      s1[nj] += __shfl_xor(s1[nj], off, 64);
      s2[nj] += __shfl_xor(s2[nj], off, 64);
    }
  if (fg == 0){
    #pragma unroll
    for (int nj=0;nj<4;++nj){
      int c = wn*64 + nj*16 + fr;
      red1[wm*128 + c] = s1[nj];
      red2[wm*128 + c] = s2[nj];
    }
  }
  __syncthreads();
  if (t < 128){
    float a  = red1[t] + red1[128+t] + red1[256+t] + red1[384+t];
    float b2 = red2[t] + red2[128+t] + red2[256+t] + red2[384+t];
    float mn = a * (1.f/512.f);
    float var = b2 * (1.f/512.f) - mn*mn;
    ms[t] = mn; rs[t] = rsqrtf(var + 1e-5f);
  }
  __syncthreads();
  float mc[4], rc[4];
  #pragma unroll
  for (int nj=0;nj<4;++nj){
    int c = wn*64 + nj*16 + fr;
    mc[nj] = ms[c]; rc[nj] = rs[c];
  }
  float* ob = out + (size_t)z*CD*NS + n0;
  #pragma unroll
  for (int mi=0;mi<8;++mi)
    #pragma unroll
    for (int r=0;r<4;++r){
      int row = wm*128 + mi*16 + fg*4 + r;
      float gg = g2[row];
      #pragma unroll
      for (int nj=0;nj<4;++nj)
        ob[(size_t)row*NS + wn*64 + nj*16 + fr] = (acc[mi][nj][r] - mc[nj])*rc[nj]*gg;
    }
}

extern "C" void kernel_launch(void* const* d_in, const int* in_sizes, int n_in,
                              void* d_out, int out_size, void* d_ws, size_t ws_size,
                              hipStream_t stream) {
  const float* fmap = (const float*)d_in[0];
  const float* g1   = (const float*)d_in[1];
  const float* wqkv = (const float*)d_in[2];
  const float* wout = (const float*)d_in[3];
  const float* g2   = (const float*)d_in[4];
  float* out = (float*)d_out;

  char* ws = (char*)d_ws;
  size_t off = 0;
  auto alloc = [&](size_t bytes) -> void* {
    void* p = ws + off;
    off += (bytes + 255) & ~(size_t)255;
    return p;
  };
  u16*   q    = (u16*)alloc((size_t)16*512*4096*2);
  u16*   xlnT = (u16*)alloc((size_t)16*4096*512*2);
  float* part = (float*)alloc((size_t)128*16*4096*4);
  float* mS   = (float*)alloc((size_t)128*16*128*4);
  float* ctx  = (float*)alloc((size_t)128*4096*4);
  u16*   w1b  = (u16*)alloc((size_t)1536*512*2);
  u16*   w2b  = (u16*)alloc((size_t)512*512*2);
  if (off > ws_size) return;

  prep_w_k<<<4096, 256, 0, stream>>>(wqkv, g1, wout, w1b, w2b);
  ln1t_k<<<dim3(128,16), 512, 0, stream>>>(fmap, xlnT);
  gemm1q_k<<<512, 512, 0, stream>>>(w1b, xlnT, q);
  gemm1kv_k<<<1024, 512, 0, stream>>>(w1b, xlnT, part, mS);
  ctxred_k<<<128, 256, 0, stream>>>(part, mS, ctx);
  gemm2f_k<<<dim3(32,16), 512, 0, stream>>>(w2b, q, ctx, g2, out);
}